// Round 3
// baseline (24164.240 us; speedup 1.0000x reference)
//
#include <hip/hip_runtime.h>
#include <hip/hip_bf16.h>
#include <math.h>

// Problem constants (DiscreteTransformer)
#define B_  8192
#define S_  16
#define E_  256
#define H_  8
#define FF_ 1024
#define L_  6
#define V_  512
#define U_  1024
#define DC_ 64
#define M_  (B_ * S_)     // 131072 tokens

// ---------------------------------------------------------------------------
// Wave (64-lane) reductions
// ---------------------------------------------------------------------------
__device__ __forceinline__ float wave_sum(float v) {
#pragma unroll
  for (int off = 32; off >= 1; off >>= 1) v += __shfl_xor(v, off);
  return v;
}
__device__ __forceinline__ float wave_max(float v) {
#pragma unroll
  for (int off = 32; off >= 1; off >>= 1) v = fmaxf(v, __shfl_xor(v, off));
  return v;
}

// ---------------------------------------------------------------------------
// GEMM: C[M,N] = act(A[M,K] @ W[N,K]^T + bias[N] (+ res[M,N]))
// A row-major [M,K], W row-major [N,K] (both K-contiguous: "TN" layout).
// Tiles: 128x128x16, 256 threads, 8x8 micro-tile per thread.
// Requires M%128==0, N%128==0, K%16==0 (all shapes here satisfy this).
// ACT: 0=none, 1=gelu(exact, erf), 2=relu.
// ---------------------------------------------------------------------------
#define BM 128
#define BN 128
#define BK 16

template <int ACT, bool RES>
__launch_bounds__(256, 2)
__global__ void gemm_kernel(const float* __restrict__ A, const float* __restrict__ W,
                            const float* __restrict__ bias, const float* __restrict__ res,
                            float* __restrict__ C, int M, int N, int K) {
  __shared__ __align__(16) float As[BK][BM + 4];
  __shared__ __align__(16) float Ws[BK][BN + 4];
  const int t  = threadIdx.x;
  const int tx = t & 15;
  const int ty = t >> 4;
  const int nbn = N / BN;
  const int bm = blockIdx.x / nbn;   // consecutive blocks sweep bn -> share A panel in L2
  const int bn = blockIdx.x % nbn;
  const int m0 = bm * BM;
  const int n0 = bn * BN;

  float acc[8][8];
#pragma unroll
  for (int i = 0; i < 8; ++i)
#pragma unroll
    for (int j = 0; j < 8; ++j) acc[i][j] = 0.f;

  for (int k0 = 0; k0 < K; k0 += BK) {
#pragma unroll
    for (int r = 0; r < 2; ++r) {
      const int f   = t + 256 * r;      // 512 float4s per 128x16 tile
      const int row = f >> 2;           // 0..127
      const int kq  = (f & 3) << 2;     // 0,4,8,12
      const float4 va = *(const float4*)&A[(size_t)(m0 + row) * K + k0 + kq];
      As[kq + 0][row] = va.x; As[kq + 1][row] = va.y;
      As[kq + 2][row] = va.z; As[kq + 3][row] = va.w;
      const float4 vw = *(const float4*)&W[(size_t)(n0 + row) * K + k0 + kq];
      Ws[kq + 0][row] = vw.x; Ws[kq + 1][row] = vw.y;
      Ws[kq + 2][row] = vw.z; Ws[kq + 3][row] = vw.w;
    }
    __syncthreads();
#pragma unroll
    for (int kk = 0; kk < BK; ++kk) {
      float ar[8], br[8];
      const float4 a0 = *(const float4*)&As[kk][ty * 8];
      const float4 a1 = *(const float4*)&As[kk][ty * 8 + 4];
      const float4 b0 = *(const float4*)&Ws[kk][tx * 8];
      const float4 b1 = *(const float4*)&Ws[kk][tx * 8 + 4];
      ar[0] = a0.x; ar[1] = a0.y; ar[2] = a0.z; ar[3] = a0.w;
      ar[4] = a1.x; ar[5] = a1.y; ar[6] = a1.z; ar[7] = a1.w;
      br[0] = b0.x; br[1] = b0.y; br[2] = b0.z; br[3] = b0.w;
      br[4] = b1.x; br[5] = b1.y; br[6] = b1.z; br[7] = b1.w;
#pragma unroll
      for (int i = 0; i < 8; ++i)
#pragma unroll
        for (int j = 0; j < 8; ++j) acc[i][j] = fmaf(ar[i], br[j], acc[i][j]);
    }
    __syncthreads();
  }

#pragma unroll
  for (int i = 0; i < 8; ++i) {
    const int m = m0 + ty * 8 + i;
#pragma unroll
    for (int jq = 0; jq < 2; ++jq) {
      const int n = n0 + tx * 8 + jq * 4;
      float v[4];
#pragma unroll
      for (int j = 0; j < 4; ++j) {
        float z = acc[i][jq * 4 + j] + bias[n + j];
        if (RES) z += res[(size_t)m * N + n + j];
        if (ACT == 1) z = 0.5f * z * (1.0f + erff(z * 0.70710678118654752f));
        if (ACT == 2) z = fmaxf(z, 0.0f);
        v[j] = z;
      }
      float4 o4; o4.x = v[0]; o4.y = v[1]; o4.z = v[2]; o4.w = v[3];
      *(float4*)&C[(size_t)m * N + n] = o4;
    }
  }
}

// ---------------------------------------------------------------------------
// Embedding (chunk-local h): h[t,:] = (s==0 ? 0 : x_emb[x[b,s-1]]) + pos_emb[s]
//                                    + cproj[b],  b = b0 + t/16, s = t%16
// One thread per float4 of h (grid covers exactly MC*64 threads).
// ---------------------------------------------------------------------------
__global__ void embed_kernel(const int* __restrict__ x, const float* __restrict__ x_emb,
                             const float* __restrict__ pos_emb, const float* __restrict__ cproj,
                             float* __restrict__ h, int b0) {
  const int idx = blockIdx.x * 256 + threadIdx.x;
  const int e4 = idx & 63;
  const int s  = (idx >> 6) & 15;
  const int b  = b0 + (idx >> 10);
  const float4 pe = ((const float4*)pos_emb)[s * 64 + e4];
  const float4 cp = ((const float4*)cproj)[b * 64 + e4];
  float4 v;
  v.x = pe.x + cp.x; v.y = pe.y + cp.y; v.z = pe.z + cp.z; v.w = pe.w + cp.w;
  if (s > 0) {
    const int tok = x[b * 16 + s - 1];
    const float4 xe = ((const float4*)x_emb)[tok * 64 + e4];
    v.x += xe.x; v.y += xe.y; v.z += xe.z; v.w += xe.w;
  }
  ((float4*)h)[idx] = v;
}

// ---------------------------------------------------------------------------
// Attention (chunk-local): per (b_local, head) on one wave. S=16, dh=32.
// qkv layout [MC, 768]: cols 0..255 q, 256..511 k, 512..767 v; head hh at hh*32.
// Causal softmax (mask t > s with -1e30, matching the reference).
// ---------------------------------------------------------------------------
__launch_bounds__(256)
__global__ void attn_kernel(const float* __restrict__ qkv, float* __restrict__ o) {
  __shared__ __align__(16) float sq[4][16][36];
  __shared__ __align__(16) float sk[4][16][36];
  __shared__ __align__(16) float sv[4][16][36];
  __shared__ float sa[4][16][17];
  const int w   = threadIdx.x >> 6;
  const int l   = threadIdx.x & 63;
  const int gid = blockIdx.x * 4 + w;   // = b_local*8 + head
  const int b   = gid >> 3;
  const int hh  = gid & 7;

  {  // cooperative load: 16 rows x 32 d, 4 lanes per row, 8 floats each
    const int s  = l >> 2;
    const int d0 = (l & 3) * 8;
    const size_t base = (size_t)(b * 16 + s) * 768 + hh * 32 + d0;
    *(float4*)&sq[w][s][d0]     = *(const float4*)&qkv[base];
    *(float4*)&sq[w][s][d0 + 4] = *(const float4*)&qkv[base + 4];
    *(float4*)&sk[w][s][d0]     = *(const float4*)&qkv[base + 256];
    *(float4*)&sk[w][s][d0 + 4] = *(const float4*)&qkv[base + 260];
    *(float4*)&sv[w][s][d0]     = *(const float4*)&qkv[base + 512];
    *(float4*)&sv[w][s][d0 + 4] = *(const float4*)&qkv[base + 516];
  }
  __syncthreads();

  {  // scores + causal softmax: lane owns row sr, 4 cols t = tq*4+j
    const int sr = l & 15;
    const int tq = l >> 4;
    float sc[4] = {0.f, 0.f, 0.f, 0.f};
    for (int d = 0; d < 32; d += 4) {
      const float4 qv = *(const float4*)&sq[w][sr][d];
#pragma unroll
      for (int j = 0; j < 4; ++j) {
        const float4 kv = *(const float4*)&sk[w][tq * 4 + j][d];
        sc[j] += qv.x * kv.x + qv.y * kv.y + qv.z * kv.z + qv.w * kv.w;
      }
    }
    float mx = -1e30f;
#pragma unroll
    for (int j = 0; j < 4; ++j) {
      const int tt = tq * 4 + j;
      sc[j] = (tt > sr) ? -1e30f : sc[j] * 0.17677669529663687f;  // 1/sqrt(32)
      mx = fmaxf(mx, sc[j]);
    }
    mx = fmaxf(mx, __shfl_xor(mx, 16));
    mx = fmaxf(mx, __shfl_xor(mx, 32));
    float e[4]; float sm = 0.f;
#pragma unroll
    for (int j = 0; j < 4; ++j) { e[j] = expf(sc[j] - mx); sm += e[j]; }
    sm += __shfl_xor(sm, 16);
    sm += __shfl_xor(sm, 32);
#pragma unroll
    for (int j = 0; j < 4; ++j) sa[w][sr][tq * 4 + j] = e[j] / sm;
  }
  __syncthreads();

  {  // o[s,d] = sum_t a[s,t] * v[t,d]
    const int s  = l >> 2;
    const int d0 = (l & 3) * 8;
    float a0[4] = {0.f, 0.f, 0.f, 0.f}, a1[4] = {0.f, 0.f, 0.f, 0.f};
    for (int tt = 0; tt < 16; ++tt) {
      const float av = sa[w][s][tt];
      const float4 v0 = *(const float4*)&sv[w][tt][d0];
      const float4 v1 = *(const float4*)&sv[w][tt][d0 + 4];
      a0[0] = fmaf(av, v0.x, a0[0]); a0[1] = fmaf(av, v0.y, a0[1]);
      a0[2] = fmaf(av, v0.z, a0[2]); a0[3] = fmaf(av, v0.w, a0[3]);
      a1[0] = fmaf(av, v1.x, a1[0]); a1[1] = fmaf(av, v1.y, a1[1]);
      a1[2] = fmaf(av, v1.z, a1[2]); a1[3] = fmaf(av, v1.w, a1[3]);
    }
    const size_t ob = (size_t)(b * 16 + s) * 256 + hh * 32 + d0;
    float4 w0; w0.x = a0[0]; w0.y = a0[1]; w0.z = a0[2]; w0.w = a0[3];
    float4 w1; w1.x = a1[0]; w1.y = a1[1]; w1.z = a1[2]; w1.w = a1[3];
    *(float4*)&o[ob]     = w0;
    *(float4*)&o[ob + 4] = w1;
  }
}

// ---------------------------------------------------------------------------
// LayerNorm over E=256: one wave per row (4 floats/lane).
// ---------------------------------------------------------------------------
__launch_bounds__(256)
__global__ void ln_kernel(const float* __restrict__ xin, const float* __restrict__ g,
                          const float* __restrict__ bb, float* __restrict__ out) {
  const int w = threadIdx.x >> 6;
  const int l = threadIdx.x & 63;
  const size_t row = (size_t)blockIdx.x * 4 + w;
  const float4 v = *(const float4*)&xin[row * 256 + l * 4];
  const float s  = wave_sum(v.x + v.y + v.z + v.w);
  const float mu = s * (1.0f / 256.0f);
  float dx[4] = {v.x - mu, v.y - mu, v.z - mu, v.w - mu};
  const float q   = wave_sum(dx[0] * dx[0] + dx[1] * dx[1] + dx[2] * dx[2] + dx[3] * dx[3]);
  const float var = q * (1.0f / 256.0f);
  const float rs  = 1.0f / sqrtf(var + 1e-5f);
  const float4 gg = *(const float4*)&g[l * 4];
  const float4 bv = *(const float4*)&bb[l * 4];
  float4 o4;
  o4.x = dx[0] * rs * gg.x + bv.x;
  o4.y = dx[1] * rs * gg.y + bv.y;
  o4.z = dx[2] * rs * gg.z + bv.z;
  o4.w = dx[3] * rs * gg.w + bv.w;
  *(float4*)&out[row * 256 + l * 4] = o4;
}

// ---------------------------------------------------------------------------
// Final: out[b] = sum_s ( logits[s_local, x[b,s]] - logsumexp_v )
// logits chunk-local [MC, 512]; one wave per b; 8 elements/lane.
// ---------------------------------------------------------------------------
__launch_bounds__(256)
__global__ void logprob_kernel(const float* __restrict__ logits, const int* __restrict__ x,
                               float* __restrict__ out, int b0) {
  const int w  = threadIdx.x >> 6;
  const int l  = threadIdx.x & 63;
  const int bl = blockIdx.x * 4 + w;   // chunk-local row
  const int b  = b0 + bl;              // global batch row
  float acc = 0.f;
  for (int s = 0; s < 16; ++s) {
    const float* row = logits + (size_t)(bl * 16 + s) * 512;
    float v[8];
#pragma unroll
    for (int i = 0; i < 8; ++i) v[i] = row[l + 64 * i];
    float mx = v[0];
#pragma unroll
    for (int i = 1; i < 8; ++i) mx = fmaxf(mx, v[i]);
    mx = wave_max(mx);
    float se = 0.f;
#pragma unroll
    for (int i = 0; i < 8; ++i) se += expf(v[i] - mx);
    se = wave_sum(se);
    const float lse = mx + logf(se);
    const float picked = row[x[b * 16 + s]];
    acc += picked - lse;
  }
  if (l == 0) out[b] = acc;
}

// ---------------------------------------------------------------------------
// Orchestration. Adaptive chunking: pick the largest BC (rows per chunk) whose
// workspace fits ws_size. Footprint (floats):
//   cpr [B_,256] (computed once) + h [BC*16,256] + R [BC*16,1024] + X [BC*16,1024]
// ws_size is constant across calls -> host-side branch is capture-safe.
// ---------------------------------------------------------------------------
extern "C" void kernel_launch(void* const* d_in, const int* in_sizes, int n_in,
                              void* d_out, int out_size, void* d_ws, size_t ws_size,
                              hipStream_t stream) {
  const int*   x       = (const int*)  d_in[0];
  const float* c       = (const float*)d_in[1];
  const float* x_emb   = (const float*)d_in[2];
  const float* pos_emb = (const float*)d_in[3];
  const float* c_W     = (const float*)d_in[4];
  const float* c_b     = (const float*)d_in[5];
  const float* Wqkv    = (const float*)d_in[6];
  const float* bqkv    = (const float*)d_in[7];
  const float* Wo      = (const float*)d_in[8];
  const float* bo      = (const float*)d_in[9];
  const float* ln1_g   = (const float*)d_in[10];
  const float* ln1_b   = (const float*)d_in[11];
  const float* W1      = (const float*)d_in[12];
  const float* b1      = (const float*)d_in[13];
  const float* W2      = (const float*)d_in[14];
  const float* b2      = (const float*)d_in[15];
  const float* ln2_g   = (const float*)d_in[16];
  const float* ln2_b   = (const float*)d_in[17];
  const float* mW0     = (const float*)d_in[18];
  const float* mb0     = (const float*)d_in[19];
  const float* mW1     = (const float*)d_in[20];
  const float* mb1     = (const float*)d_in[21];
  const float* mW2     = (const float*)d_in[22];
  const float* mb2     = (const float*)d_in[23];
  float* out = (float*)d_out;

  // Pick largest chunk that fits: need = B_*256 + BC*16*(256+1024+1024) floats.
  const size_t avail = ws_size / sizeof(float);
  int BC = 0;
  for (int bc = B_; bc >= 128; bc >>= 1) {
    const size_t need = (size_t)B_ * 256 + (size_t)bc * 16 * 2304;
    if (need <= avail) { BC = bc; break; }
  }
  if (BC == 0) return;  // scratch < 27 MB: fail visibly via graph node count
  const int MC = BC * 16;
  const int NCHUNK = B_ / BC;

  float* cpr = (float*)d_ws;
  float* h   = cpr + (size_t)B_ * 256;
  float* R   = h   + (size_t)MC * 256;
  float* X   = R   + (size_t)MC * 1024;

  const dim3 blk(256);

  // cproj = c @ c_W^T + c_b   [B_,256], K=64  (whole batch, once)
  gemm_kernel<0, false><<<dim3((B_ / BM) * (E_ / BN)), blk, 0, stream>>>(
      c, c_W, c_b, nullptr, cpr, B_, E_, DC_);

  for (int ci = 0; ci < NCHUNK; ++ci) {
    const int b0 = ci * BC;
    // h = shifted-embed + pos + cproj
    embed_kernel<<<dim3((MC * 64) / 256), blk, 0, stream>>>(x, x_emb, pos_emb, cpr, h, b0);

    for (int l = 0; l < L_; ++l) {
      // qkv = h @ Wqkv^T + bqkv   [MC,768], K=256  -> R
      gemm_kernel<0, false><<<dim3((MC / BM) * (768 / BN)), blk, 0, stream>>>(
          h, Wqkv + (size_t)l * 768 * 256, bqkv + (size_t)l * 768, nullptr, R, MC, 768, 256);
      // o = attention(qkv)   [MC,256]  -> X
      attn_kernel<<<dim3(BC * 2), blk, 0, stream>>>(R, X);
      // preLN = o @ Wo^T + bo + h   [MC,256], K=256  -> R
      gemm_kernel<0, true><<<dim3((MC / BM) * (E_ / BN)), blk, 0, stream>>>(
          X, Wo + (size_t)l * 256 * 256, bo + (size_t)l * 256, h, R, MC, 256, 256);
      // h = LN1(preLN)
      ln_kernel<<<dim3(MC / 4), blk, 0, stream>>>(R, ln1_g + (size_t)l * 256,
                                                  ln1_b + (size_t)l * 256, h);
      // f = gelu(h @ W1^T + b1)   [MC,1024], K=256  -> R
      gemm_kernel<1, false><<<dim3((MC / BM) * (FF_ / BN)), blk, 0, stream>>>(
          h, W1 + (size_t)l * 1024 * 256, b1 + (size_t)l * 1024, nullptr, R, MC, 1024, 256);
      // preLN = f @ W2^T + b2 + h   [MC,256], K=1024  -> X
      gemm_kernel<0, true><<<dim3((MC / BM) * (E_ / BN)), blk, 0, stream>>>(
          R, W2 + (size_t)l * 256 * 1024, b2 + (size_t)l * 256, h, X, MC, 256, 1024);
      // h = LN2(preLN)
      ln_kernel<<<dim3(MC / 4), blk, 0, stream>>>(X, ln2_g + (size_t)l * 256,
                                                  ln2_b + (size_t)l * 256, h);
    }

    // Head MLP (chunk-local)
    gemm_kernel<2, false><<<dim3((MC / BM) * (U_ / BN)), blk, 0, stream>>>(
        h, mW0, mb0, nullptr, R, MC, U_, E_);            // z0 = relu(h@mW0^T+mb0) -> R
    gemm_kernel<2, false><<<dim3((MC / BM) * (U_ / BN)), blk, 0, stream>>>(
        R, mW1, mb1, nullptr, X, MC, U_, U_);            // z1 = relu(z0@mW1^T+mb1) -> X
    gemm_kernel<0, false><<<dim3((MC / BM) * (V_ / BN)), blk, 0, stream>>>(
        X, mW2, mb2, nullptr, R, MC, V_, U_);            // logits = z1@mW2^T+mb2 -> R

    // out[b] = sum_s (logits[b,s,x[b,s]] - LSE)
    logprob_kernel<<<dim3(BC / 4), blk, 0, stream>>>(R, x, out, b0);
  }
}

// Round 4
// 10743.660 us; speedup vs baseline: 2.2492x; 2.2492x over previous
//
#include <hip/hip_runtime.h>
#include <hip/hip_bf16.h>
#include <math.h>

// Problem constants (DiscreteTransformer)
#define B_  8192
#define S_  16
#define E_  256
#define H_  8
#define FF_ 1024
#define L_  6
#define V_  512
#define U_  1024
#define DC_ 64
#define M_  (B_ * S_)     // 131072 tokens

typedef __attribute__((ext_vector_type(8))) short short8;   // 8 bf16 (4 VGPRs)
typedef __attribute__((ext_vector_type(4))) float f32x4;

// ---------------------------------------------------------------------------
// Wave (64-lane) reductions
// ---------------------------------------------------------------------------
__device__ __forceinline__ float wave_sum(float v) {
#pragma unroll
  for (int off = 32; off >= 1; off >>= 1) v += __shfl_xor(v, off);
  return v;
}
__device__ __forceinline__ float wave_max(float v) {
#pragma unroll
  for (int off = 32; off >= 1; off >>= 1) v = fmaxf(v, __shfl_xor(v, off));
  return v;
}

// fp32 -> bf16 (RNE), packed pair into one dword
__device__ __forceinline__ unsigned bfround(float f) {
  unsigned u = __builtin_bit_cast(unsigned, f);
  return (u + 0x7FFFu + ((u >> 16) & 1u)) >> 16;
}
__device__ __forceinline__ unsigned pack2(float lo, float hi) {
  return bfround(lo) | (bfround(hi) << 16);
}

// ---------------------------------------------------------------------------
// Weight fp32 -> bf16 conversion (grid-stride-free: exact grid, n % 1024 == 0)
// ---------------------------------------------------------------------------
__global__ void w2bf_kernel(const float* __restrict__ src, short* __restrict__ dst) {
  const int i = blockIdx.x * 256 + threadIdx.x;  // over n/4
  const float4 v = ((const float4*)src)[i];
  uint2 p;
  p.x = pack2(v.x, v.y);
  p.y = pack2(v.z, v.w);
  ((uint2*)dst)[i] = p;
}

// ---------------------------------------------------------------------------
// bf16-MFMA GEMM: C[M,N] = act(A[M,K] @ W[N,K]^T + bias[N] (+ res[M,N]))
// A fp32 row-major (converted to bf16 during LDS staging); W bf16 row-major
// [N,K] (pre-converted). fp32 accumulation via v_mfma_f32_16x16x32_bf16.
// Tile 128x128xBK64; 256 threads = 4 waves in 2x2 grid; 4x4 16x16 frags/wave.
// LDS [128][72] bf16 (+8 pad -> uniform bank use on ds_read_b128).
// Requires M%128==0, N%128==0, K%64==0 (all shapes here satisfy this).
// ACT: 0=none, 1=gelu(exact, erf), 2=relu.
// ---------------------------------------------------------------------------
template <int ACT, bool RES>
__launch_bounds__(256, 2)
__global__ void gemm_bf16_kernel(const float* __restrict__ A, const short* __restrict__ W,
                                 const float* __restrict__ bias, const float* __restrict__ res,
                                 float* __restrict__ C, int M, int N, int K) {
  __shared__ __align__(16) short As[128][72];
  __shared__ __align__(16) short Ws[128][72];
  const int t  = threadIdx.x;
  const int w  = t >> 6;          // wave 0..3
  const int l  = t & 63;
  const int wr = w >> 1;          // wave row (2)
  const int wc = w & 1;           // wave col (2)
  const int lr = l & 15;          // fragment row/col lane
  const int kg = l >> 4;          // k-group 0..3
  const int nbn = N / 128;
  const int bm = blockIdx.x / nbn;  // consecutive blocks sweep bn -> A panel L2 reuse
  const int bn = blockIdx.x % nbn;
  const int m0 = bm * 128, n0 = bn * 128;

  f32x4 acc[4][4] = {};

  // staging: thread t covers row sr, 32-col half sc
  const int sr = t >> 1;
  const int sc = (t & 1) * 32;

  for (int k0 = 0; k0 < K; k0 += 64) {
    const float* Ap = &A[(size_t)(m0 + sr) * K + k0 + sc];
    float4 av[8];
#pragma unroll
    for (int q = 0; q < 8; ++q) av[q] = ((const float4*)Ap)[q];
    const short* Wp = &W[(size_t)(n0 + sr) * K + k0 + sc];
    uint4 wv[4];
#pragma unroll
    for (int q = 0; q < 4; ++q) wv[q] = ((const uint4*)Wp)[q];
#pragma unroll
    for (int q = 0; q < 4; ++q) {
      uint4 p;
      p.x = pack2(av[2 * q].x,     av[2 * q].y);
      p.y = pack2(av[2 * q].z,     av[2 * q].w);
      p.z = pack2(av[2 * q + 1].x, av[2 * q + 1].y);
      p.w = pack2(av[2 * q + 1].z, av[2 * q + 1].w);
      *(uint4*)&As[sr][sc + q * 8] = p;
    }
#pragma unroll
    for (int q = 0; q < 4; ++q) *(uint4*)&Ws[sr][sc + q * 8] = wv[q];
    __syncthreads();

#pragma unroll
    for (int kk = 0; kk < 64; kk += 32) {
      short8 af[4], bf[4];
#pragma unroll
      for (int mi = 0; mi < 4; ++mi)
        af[mi] = *(const short8*)&As[wr * 64 + mi * 16 + lr][kk + kg * 8];
#pragma unroll
      for (int ni = 0; ni < 4; ++ni)
        bf[ni] = *(const short8*)&Ws[wc * 64 + ni * 16 + lr][kk + kg * 8];
#pragma unroll
      for (int mi = 0; mi < 4; ++mi)
#pragma unroll
        for (int ni = 0; ni < 4; ++ni)
          acc[mi][ni] = __builtin_amdgcn_mfma_f32_16x16x32_bf16(af[mi], bf[ni], acc[mi][ni], 0, 0, 0);
    }
    __syncthreads();
  }

  // epilogue: C/D layout col=l&15, row=(l>>4)*4+j  [m89-verified]
#pragma unroll
  for (int ni = 0; ni < 4; ++ni) {
    const int n = n0 + wc * 64 + ni * 16 + lr;
    const float bv = bias[n];
#pragma unroll
    for (int mi = 0; mi < 4; ++mi) {
      const int mbase = m0 + wr * 64 + mi * 16 + kg * 4;
#pragma unroll
      for (int j = 0; j < 4; ++j) {
        float z = acc[mi][ni][j] + bv;
        const size_t off = (size_t)(mbase + j) * N + n;
        if (RES) z += res[off];
        if (ACT == 1) z = 0.5f * z * (1.0f + erff(z * 0.70710678118654752f));
        if (ACT == 2) z = fmaxf(z, 0.0f);
        C[off] = z;
      }
    }
  }
}

// ---------------------------------------------------------------------------
// Embedding (chunk-local h): h[t,:] = (s==0 ? 0 : x_emb[x[b,s-1]]) + pos_emb[s]
//                                    + cproj[b],  b = b0 + t/16, s = t%16
// ---------------------------------------------------------------------------
__global__ void embed_kernel(const int* __restrict__ x, const float* __restrict__ x_emb,
                             const float* __restrict__ pos_emb, const float* __restrict__ cproj,
                             float* __restrict__ h, int b0) {
  const int idx = blockIdx.x * 256 + threadIdx.x;
  const int e4 = idx & 63;
  const int s  = (idx >> 6) & 15;
  const int b  = b0 + (idx >> 10);
  const float4 pe = ((const float4*)pos_emb)[s * 64 + e4];
  const float4 cp = ((const float4*)cproj)[b * 64 + e4];
  float4 v;
  v.x = pe.x + cp.x; v.y = pe.y + cp.y; v.z = pe.z + cp.z; v.w = pe.w + cp.w;
  if (s > 0) {
    const int tok = x[b * 16 + s - 1];
    const float4 xe = ((const float4*)x_emb)[tok * 64 + e4];
    v.x += xe.x; v.y += xe.y; v.z += xe.z; v.w += xe.w;
  }
  ((float4*)h)[idx] = v;
}

// ---------------------------------------------------------------------------
// Attention (chunk-local): per (b_local, head) on one wave. S=16, dh=32.
// ---------------------------------------------------------------------------
__launch_bounds__(256)
__global__ void attn_kernel(const float* __restrict__ qkv, float* __restrict__ o) {
  __shared__ __align__(16) float sq[4][16][36];
  __shared__ __align__(16) float sk[4][16][36];
  __shared__ __align__(16) float sv[4][16][36];
  __shared__ float sa[4][16][17];
  const int w   = threadIdx.x >> 6;
  const int l   = threadIdx.x & 63;
  const int gid = blockIdx.x * 4 + w;   // = b_local*8 + head
  const int b   = gid >> 3;
  const int hh  = gid & 7;

  {
    const int s  = l >> 2;
    const int d0 = (l & 3) * 8;
    const size_t base = (size_t)(b * 16 + s) * 768 + hh * 32 + d0;
    *(float4*)&sq[w][s][d0]     = *(const float4*)&qkv[base];
    *(float4*)&sq[w][s][d0 + 4] = *(const float4*)&qkv[base + 4];
    *(float4*)&sk[w][s][d0]     = *(const float4*)&qkv[base + 256];
    *(float4*)&sk[w][s][d0 + 4] = *(const float4*)&qkv[base + 260];
    *(float4*)&sv[w][s][d0]     = *(const float4*)&qkv[base + 512];
    *(float4*)&sv[w][s][d0 + 4] = *(const float4*)&qkv[base + 516];
  }
  __syncthreads();

  {
    const int sr = l & 15;
    const int tq = l >> 4;
    float sc[4] = {0.f, 0.f, 0.f, 0.f};
    for (int d = 0; d < 32; d += 4) {
      const float4 qv = *(const float4*)&sq[w][sr][d];
#pragma unroll
      for (int j = 0; j < 4; ++j) {
        const float4 kv = *(const float4*)&sk[w][tq * 4 + j][d];
        sc[j] += qv.x * kv.x + qv.y * kv.y + qv.z * kv.z + qv.w * kv.w;
      }
    }
    float mx = -1e30f;
#pragma unroll
    for (int j = 0; j < 4; ++j) {
      const int tt = tq * 4 + j;
      sc[j] = (tt > sr) ? -1e30f : sc[j] * 0.17677669529663687f;  // 1/sqrt(32)
      mx = fmaxf(mx, sc[j]);
    }
    mx = fmaxf(mx, __shfl_xor(mx, 16));
    mx = fmaxf(mx, __shfl_xor(mx, 32));
    float e[4]; float sm = 0.f;
#pragma unroll
    for (int j = 0; j < 4; ++j) { e[j] = expf(sc[j] - mx); sm += e[j]; }
    sm += __shfl_xor(sm, 16);
    sm += __shfl_xor(sm, 32);
#pragma unroll
    for (int j = 0; j < 4; ++j) sa[w][sr][tq * 4 + j] = e[j] / sm;
  }
  __syncthreads();

  {
    const int s  = l >> 2;
    const int d0 = (l & 3) * 8;
    float a0[4] = {0.f, 0.f, 0.f, 0.f}, a1[4] = {0.f, 0.f, 0.f, 0.f};
    for (int tt = 0; tt < 16; ++tt) {
      const float av = sa[w][s][tt];
      const float4 v0 = *(const float4*)&sv[w][tt][d0];
      const float4 v1 = *(const float4*)&sv[w][tt][d0 + 4];
      a0[0] = fmaf(av, v0.x, a0[0]); a0[1] = fmaf(av, v0.y, a0[1]);
      a0[2] = fmaf(av, v0.z, a0[2]); a0[3] = fmaf(av, v0.w, a0[3]);
      a1[0] = fmaf(av, v1.x, a1[0]); a1[1] = fmaf(av, v1.y, a1[1]);
      a1[2] = fmaf(av, v1.z, a1[2]); a1[3] = fmaf(av, v1.w, a1[3]);
    }
    const size_t ob = (size_t)(b * 16 + s) * 256 + hh * 32 + d0;
    float4 w0; w0.x = a0[0]; w0.y = a0[1]; w0.z = a0[2]; w0.w = a0[3];
    float4 w1; w1.x = a1[0]; w1.y = a1[1]; w1.z = a1[2]; w1.w = a1[3];
    *(float4*)&o[ob]     = w0;
    *(float4*)&o[ob + 4] = w1;
  }
}

// ---------------------------------------------------------------------------
// LayerNorm over E=256: one wave per row (4 floats/lane).
// ---------------------------------------------------------------------------
__launch_bounds__(256)
__global__ void ln_kernel(const float* __restrict__ xin, const float* __restrict__ g,
                          const float* __restrict__ bb, float* __restrict__ out) {
  const int w = threadIdx.x >> 6;
  const int l = threadIdx.x & 63;
  const size_t row = (size_t)blockIdx.x * 4 + w;
  const float4 v = *(const float4*)&xin[row * 256 + l * 4];
  const float s  = wave_sum(v.x + v.y + v.z + v.w);
  const float mu = s * (1.0f / 256.0f);
  float dx[4] = {v.x - mu, v.y - mu, v.z - mu, v.w - mu};
  const float q   = wave_sum(dx[0] * dx[0] + dx[1] * dx[1] + dx[2] * dx[2] + dx[3] * dx[3]);
  const float var = q * (1.0f / 256.0f);
  const float rs  = 1.0f / sqrtf(var + 1e-5f);
  const float4 gg = *(const float4*)&g[l * 4];
  const float4 bv = *(const float4*)&bb[l * 4];
  float4 o4;
  o4.x = dx[0] * rs * gg.x + bv.x;
  o4.y = dx[1] * rs * gg.y + bv.y;
  o4.z = dx[2] * rs * gg.z + bv.z;
  o4.w = dx[3] * rs * gg.w + bv.w;
  *(float4*)&out[row * 256 + l * 4] = o4;
}

// ---------------------------------------------------------------------------
// Final: out[b] = sum_s ( logits[s_local, x[b,s]] - logsumexp_v )
// ---------------------------------------------------------------------------
__launch_bounds__(256)
__global__ void logprob_kernel(const float* __restrict__ logits, const int* __restrict__ x,
                               float* __restrict__ out, int b0) {
  const int w  = threadIdx.x >> 6;
  const int l  = threadIdx.x & 63;
  const int bl = blockIdx.x * 4 + w;
  const int b  = b0 + bl;
  float acc = 0.f;
  for (int s = 0; s < 16; ++s) {
    const float* row = logits + (size_t)(bl * 16 + s) * 512;
    float v[8];
#pragma unroll
    for (int i = 0; i < 8; ++i) v[i] = row[l + 64 * i];
    float mx = v[0];
#pragma unroll
    for (int i = 1; i < 8; ++i) mx = fmaxf(mx, v[i]);
    mx = wave_max(mx);
    float se = 0.f;
#pragma unroll
    for (int i = 0; i < 8; ++i) se += expf(v[i] - mx);
    se = wave_sum(se);
    const float lse = mx + logf(se);
    const float picked = row[x[b * 16 + s]];
    acc += picked - lse;
  }
  if (l == 0) out[b] = acc;
}

// ---------------------------------------------------------------------------
// Orchestration. Workspace: bf16 weights (13.14 MB) | cpr [B_,256] f32 |
// h [MC,256] f32 | R [MC,1024] f32 | X [MC,1024] f32.  Adaptive BC chunking.
// ---------------------------------------------------------------------------
extern "C" void kernel_launch(void* const* d_in, const int* in_sizes, int n_in,
                              void* d_out, int out_size, void* d_ws, size_t ws_size,
                              hipStream_t stream) {
  const int*   x       = (const int*)  d_in[0];
  const float* c       = (const float*)d_in[1];
  const float* x_emb   = (const float*)d_in[2];
  const float* pos_emb = (const float*)d_in[3];
  const float* c_W     = (const float*)d_in[4];
  const float* c_b     = (const float*)d_in[5];
  const float* Wqkv    = (const float*)d_in[6];
  const float* bqkv    = (const float*)d_in[7];
  const float* Wo      = (const float*)d_in[8];
  const float* bo      = (const float*)d_in[9];
  const float* ln1_g   = (const float*)d_in[10];
  const float* ln1_b   = (const float*)d_in[11];
  const float* W1      = (const float*)d_in[12];
  const float* b1      = (const float*)d_in[13];
  const float* W2      = (const float*)d_in[14];
  const float* b2      = (const float*)d_in[15];
  const float* ln2_g   = (const float*)d_in[16];
  const float* ln2_b   = (const float*)d_in[17];
  const float* mW0     = (const float*)d_in[18];
  const float* mb0     = (const float*)d_in[19];
  const float* mW1     = (const float*)d_in[20];
  const float* mb1     = (const float*)d_in[21];
  const float* mW2     = (const float*)d_in[22];
  const float* mb2     = (const float*)d_in[23];
  float* out = (float*)d_out;

  // bf16 weight region layout (element counts)
  const size_t nWqkv = (size_t)L_ * 768 * 256;   // 1,179,648
  const size_t nWo   = (size_t)L_ * 256 * 256;   //   393,216
  const size_t nW1   = (size_t)L_ * 1024 * 256;  // 1,572,864
  const size_t nW2   = (size_t)L_ * 256 * 1024;  // 1,572,864
  const size_t nmW0  = (size_t)U_ * E_;          //   262,144
  const size_t nmW1  = (size_t)U_ * U_;          // 1,048,576
  const size_t nmW2  = (size_t)V_ * U_;          //   524,288
  const size_t ncW   = (size_t)E_ * DC_;         //    16,384
  const size_t WBF   = nWqkv + nWo + nW1 + nW2 + nmW0 + nmW1 + nmW2 + ncW;  // 6,569,984

  short* wb    = (short*)d_ws;
  short* bWqkv = wb;
  short* bWo   = bWqkv + nWqkv;
  short* bW1   = bWo   + nWo;
  short* bW2   = bW1   + nW1;
  short* bmW0  = bW2   + nW2;
  short* bmW1  = bmW0  + nmW0;
  short* bmW2  = bmW1  + nmW1;
  short* bcW   = bmW2  + nmW2;

  // Pick largest chunk (rows) that fits after the bf16-weight region.
  const size_t fixed_bytes = WBF * 2 + (size_t)B_ * 256 * 4;
  int BC = 0;
  for (int bc = B_; bc >= 128; bc >>= 1) {
    const size_t need = fixed_bytes + (size_t)bc * 16 * 2304 * 4;
    if (need <= ws_size) { BC = bc; break; }
  }
  if (BC == 0) return;  // fail visibly via graph node count
  const int MC = BC * 16;
  const int NCHUNK = B_ / BC;

  float* cpr = (float*)((char*)d_ws + WBF * 2);
  float* h   = cpr + (size_t)B_ * 256;
  float* R   = h   + (size_t)MC * 256;
  float* X   = R   + (size_t)MC * 1024;

  const dim3 blk(256);

  // Convert all weights fp32 -> bf16 (every call; d_ws is re-poisoned).
  w2bf_kernel<<<dim3(nWqkv / 1024), blk, 0, stream>>>(Wqkv, bWqkv);
  w2bf_kernel<<<dim3(nWo   / 1024), blk, 0, stream>>>(Wo,   bWo);
  w2bf_kernel<<<dim3(nW1   / 1024), blk, 0, stream>>>(W1,   bW1);
  w2bf_kernel<<<dim3(nW2   / 1024), blk, 0, stream>>>(W2,   bW2);
  w2bf_kernel<<<dim3(nmW0  / 1024), blk, 0, stream>>>(mW0,  bmW0);
  w2bf_kernel<<<dim3(nmW1  / 1024), blk, 0, stream>>>(mW1,  bmW1);
  w2bf_kernel<<<dim3(nmW2  / 1024), blk, 0, stream>>>(mW2,  bmW2);
  w2bf_kernel<<<dim3(ncW   / 1024), blk, 0, stream>>>(c_W,  bcW);

  // cproj = c @ c_W^T + c_b   [B_,256], K=64  (whole batch, once)
  gemm_bf16_kernel<0, false><<<dim3((B_ / 128) * (E_ / 128)), blk, 0, stream>>>(
      c, bcW, c_b, nullptr, cpr, B_, E_, DC_);

  for (int ci = 0; ci < NCHUNK; ++ci) {
    const int b0 = ci * BC;
    embed_kernel<<<dim3((MC * 64) / 256), blk, 0, stream>>>(x, x_emb, pos_emb, cpr, h, b0);

    for (int l = 0; l < L_; ++l) {
      // qkv = h @ Wqkv^T + bqkv   [MC,768], K=256  -> R
      gemm_bf16_kernel<0, false><<<dim3((MC / 128) * (768 / 128)), blk, 0, stream>>>(
          h, bWqkv + (size_t)l * 768 * 256, bqkv + (size_t)l * 768, nullptr, R, MC, 768, 256);
      // o = attention(qkv)   [MC,256]  -> X
      attn_kernel<<<dim3(BC * 2), blk, 0, stream>>>(R, X);
      // preLN = o @ Wo^T + bo + h   [MC,256], K=256  -> R
      gemm_bf16_kernel<0, true><<<dim3((MC / 128) * (E_ / 128)), blk, 0, stream>>>(
          X, bWo + (size_t)l * 256 * 256, bo + (size_t)l * 256, h, R, MC, 256, 256);
      // h = LN1(preLN)
      ln_kernel<<<dim3(MC / 4), blk, 0, stream>>>(R, ln1_g + (size_t)l * 256,
                                                  ln1_b + (size_t)l * 256, h);
      // f = gelu(h @ W1^T + b1)   [MC,1024], K=256  -> R
      gemm_bf16_kernel<1, false><<<dim3((MC / 128) * (FF_ / 128)), blk, 0, stream>>>(
          h, bW1 + (size_t)l * 1024 * 256, b1 + (size_t)l * 1024, nullptr, R, MC, 1024, 256);
      // preLN = f @ W2^T + b2 + h   [MC,256], K=1024  -> X
      gemm_bf16_kernel<0, true><<<dim3((MC / 128) * (E_ / 128)), blk, 0, stream>>>(
          R, bW2 + (size_t)l * 256 * 1024, b2 + (size_t)l * 256, h, X, MC, 256, 1024);
      // h = LN2(preLN)
      ln_kernel<<<dim3(MC / 4), blk, 0, stream>>>(X, ln2_g + (size_t)l * 256,
                                                  ln2_b + (size_t)l * 256, h);
    }

    // Head MLP (chunk-local)
    gemm_bf16_kernel<2, false><<<dim3((MC / 128) * (U_ / 128)), blk, 0, stream>>>(
        h, bmW0, mb0, nullptr, R, MC, U_, E_);           // z0 = relu(.) -> R
    gemm_bf16_kernel<2, false><<<dim3((MC / 128) * (U_ / 128)), blk, 0, stream>>>(
        R, bmW1, mb1, nullptr, X, MC, U_, U_);           // z1 = relu(.) -> X
    gemm_bf16_kernel<0, false><<<dim3((MC / 128) * (V_ / 128)), blk, 0, stream>>>(
        X, bmW2, mb2, nullptr, R, MC, V_, U_);           // logits -> R

    logprob_kernel<<<dim3(BC / 4), blk, 0, stream>>>(R, x, out, b0);
  }
}

// Round 5
// 6905.511 us; speedup vs baseline: 3.4993x; 1.5558x over previous
//
#include <hip/hip_runtime.h>
#include <hip/hip_bf16.h>
#include <math.h>

// Problem constants (DiscreteTransformer)
#define B_  8192
#define S_  16
#define E_  256
#define H_  8
#define FF_ 1024
#define L_  6
#define V_  512
#define U_  1024
#define DC_ 64
#define M_  (B_ * S_)     // 131072 tokens

typedef __attribute__((ext_vector_type(8))) short short8;   // 8 bf16 (4 VGPRs)
typedef __attribute__((ext_vector_type(4))) float f32x4;

// ---------------------------------------------------------------------------
// Wave (64-lane) reductions
// ---------------------------------------------------------------------------
__device__ __forceinline__ float wave_sum(float v) {
#pragma unroll
  for (int off = 32; off >= 1; off >>= 1) v += __shfl_xor(v, off);
  return v;
}
__device__ __forceinline__ float wave_max(float v) {
#pragma unroll
  for (int off = 32; off >= 1; off >>= 1) v = fmaxf(v, __shfl_xor(v, off));
  return v;
}

// bf16 <-> fp32 helpers (bf16 stored as short; RNE rounding on the way down)
__device__ __forceinline__ unsigned bfround(float f) {
  unsigned u = __builtin_bit_cast(unsigned, f);
  return (u + 0x7FFFu + ((u >> 16) & 1u)) >> 16;
}
__device__ __forceinline__ unsigned pack2(float lo, float hi) {
  return bfround(lo) | (bfround(hi) << 16);
}
__device__ __forceinline__ float b2f(short s) {
  return __builtin_bit_cast(float, (unsigned)(unsigned short)s << 16);
}
__device__ __forceinline__ float blo(unsigned u) { return __builtin_bit_cast(float, u << 16); }
__device__ __forceinline__ float bhi(unsigned u) { return __builtin_bit_cast(float, u & 0xFFFF0000u); }

// ---------------------------------------------------------------------------
// fp32 -> bf16 bulk conversion (exact grid; n % 1024 == 0)
// ---------------------------------------------------------------------------
__global__ void w2bf_kernel(const float* __restrict__ src, short* __restrict__ dst) {
  const int i = blockIdx.x * 256 + threadIdx.x;  // over n/4
  const float4 v = ((const float4*)src)[i];
  uint2 p;
  p.x = pack2(v.x, v.y);
  p.y = pack2(v.z, v.w);
  ((uint2*)dst)[i] = p;
}

// ---------------------------------------------------------------------------
// bf16-MFMA GEMM: C[M,N] = act(A[M,K] @ W[N,K]^T + bias[N] (+ res[M,N]))
// A,W bf16 row-major K-contiguous. fp32 accum via v_mfma_f32_16x16x32_bf16.
// Tile 128x128xBK64; 256 threads = 4 waves (2x2); 4x4 16x16 frags/wave.
// LDS [128][72] bf16 (+8 pad: row stride 144B = 36 banks -> 2-way max, free).
// Requires M%128==0, N%128==0, K%64==0. ACT: 0=none,1=gelu(erf),2=relu.
// OUTF32: write fp32 C (for cproj / logits), else bf16.
// ---------------------------------------------------------------------------
template <int ACT, bool RES, bool OUTF32>
__launch_bounds__(256, 2)
__global__ void gemm_bf16_kernel(const short* __restrict__ A, const short* __restrict__ W,
                                 const float* __restrict__ bias, const short* __restrict__ res,
                                 void* __restrict__ Cv, int M, int N, int K) {
  __shared__ __align__(16) short As[128][72];
  __shared__ __align__(16) short Ws[128][72];
  const int t  = threadIdx.x;
  const int w  = t >> 6;          // wave 0..3
  const int l  = t & 63;
  const int wr = w >> 1;          // wave row (2)
  const int wc = w & 1;           // wave col (2)
  const int lr = l & 15;          // fragment row/col lane
  const int kg = l >> 4;          // k-group 0..3
  const int nbn = N / 128;
  const int bm = blockIdx.x / nbn;  // consecutive blocks sweep bn -> A panel L2 reuse
  const int bn = blockIdx.x % nbn;
  const int m0 = bm * 128, n0 = bn * 128;

  f32x4 acc[4][4] = {};

  // staging: thread t covers row sr, 32-col half sc (64B per operand)
  const int sr = t >> 1;
  const int sc = (t & 1) * 32;

  for (int k0 = 0; k0 < K; k0 += 64) {
    const short* Ap = &A[(size_t)(m0 + sr) * K + k0 + sc];
    const short* Wp = &W[(size_t)(n0 + sr) * K + k0 + sc];
    uint4 av[4], wv[4];
#pragma unroll
    for (int q = 0; q < 4; ++q) av[q] = ((const uint4*)Ap)[q];
#pragma unroll
    for (int q = 0; q < 4; ++q) wv[q] = ((const uint4*)Wp)[q];
#pragma unroll
    for (int q = 0; q < 4; ++q) *(uint4*)&As[sr][sc + q * 8] = av[q];
#pragma unroll
    for (int q = 0; q < 4; ++q) *(uint4*)&Ws[sr][sc + q * 8] = wv[q];
    __syncthreads();

#pragma unroll
    for (int kk = 0; kk < 64; kk += 32) {
      short8 af[4], bf[4];
#pragma unroll
      for (int mi = 0; mi < 4; ++mi)
        af[mi] = *(const short8*)&As[wr * 64 + mi * 16 + lr][kk + kg * 8];
#pragma unroll
      for (int ni = 0; ni < 4; ++ni)
        bf[ni] = *(const short8*)&Ws[wc * 64 + ni * 16 + lr][kk + kg * 8];
#pragma unroll
      for (int mi = 0; mi < 4; ++mi)
#pragma unroll
        for (int ni = 0; ni < 4; ++ni)
          acc[mi][ni] = __builtin_amdgcn_mfma_f32_16x16x32_bf16(af[mi], bf[ni], acc[mi][ni], 0, 0, 0);
    }
    __syncthreads();
  }

  float* Cf = (float*)Cv;
  short* Cb = (short*)Cv;
  // epilogue: C/D layout col=l&15, row=(l>>4)*4+j  [m89-verified]
#pragma unroll
  for (int ni = 0; ni < 4; ++ni) {
    const int n = n0 + wc * 64 + ni * 16 + lr;
    const float bv = bias[n];
#pragma unroll
    for (int mi = 0; mi < 4; ++mi) {
      const int mbase = m0 + wr * 64 + mi * 16 + kg * 4;
#pragma unroll
      for (int j = 0; j < 4; ++j) {
        float z = acc[mi][ni][j] + bv;
        const size_t off = (size_t)(mbase + j) * N + n;
        if (RES) z += b2f(res[off]);
        if (ACT == 1) z = 0.5f * z * (1.0f + erff(z * 0.70710678118654752f));
        if (ACT == 2) z = fmaxf(z, 0.0f);
        if (OUTF32) Cf[off] = z;
        else        Cb[off] = (short)bfround(z);
      }
    }
  }
}

// ---------------------------------------------------------------------------
// Embedding (chunk-local bf16 h): h[t,:] = (s==0?0:x_emb[x[b,s-1]]) + pos_emb[s]
//                                         + cproj[b],  b = b0 + t/16, s = t%16
// One thread per 4 elements of h.
// ---------------------------------------------------------------------------
__global__ void embed_kernel(const int* __restrict__ x, const float* __restrict__ x_emb,
                             const float* __restrict__ pos_emb, const float* __restrict__ cproj,
                             short* __restrict__ h, int b0) {
  const int idx = blockIdx.x * 256 + threadIdx.x;
  const int e4 = idx & 63;
  const int s  = (idx >> 6) & 15;
  const int b  = b0 + (idx >> 10);
  const float4 pe = ((const float4*)pos_emb)[s * 64 + e4];
  const float4 cp = ((const float4*)cproj)[b * 64 + e4];
  float4 v;
  v.x = pe.x + cp.x; v.y = pe.y + cp.y; v.z = pe.z + cp.z; v.w = pe.w + cp.w;
  if (s > 0) {
    const int tok = x[b * 16 + s - 1];
    const float4 xe = ((const float4*)x_emb)[tok * 64 + e4];
    v.x += xe.x; v.y += xe.y; v.z += xe.z; v.w += xe.w;
  }
  uint2 p;
  p.x = pack2(v.x, v.y);
  p.y = pack2(v.z, v.w);
  ((uint2*)h)[idx] = p;
}

// ---------------------------------------------------------------------------
// Attention (chunk-local, bf16 I/O): per (b_local, head) on one wave. S=16, dh=32.
// qkv [MC,768] bf16: 0..255 q, 256..511 k, 512..767 v; head hh at hh*32.
// ---------------------------------------------------------------------------
__launch_bounds__(256)
__global__ void attn_kernel(const short* __restrict__ qkv, short* __restrict__ o) {
  __shared__ __align__(16) float sq[4][16][36];
  __shared__ __align__(16) float sk[4][16][36];
  __shared__ __align__(16) float sv[4][16][36];
  __shared__ float sa[4][16][17];
  const int w   = threadIdx.x >> 6;
  const int l   = threadIdx.x & 63;
  const int gid = blockIdx.x * 4 + w;   // = b_local*8 + head
  const int b   = gid >> 3;
  const int hh  = gid & 7;

  {  // cooperative load+convert: 16 rows x 32 d, 4 lanes/row, 8 bf16 per seg
    const int s  = l >> 2;
    const int d0 = (l & 3) * 8;
    const size_t base = (size_t)(b * 16 + s) * 768 + hh * 32 + d0;
    const uint4 qv = *(const uint4*)&qkv[base];
    const uint4 kv = *(const uint4*)&qkv[base + 256];
    const uint4 vv = *(const uint4*)&qkv[base + 512];
    float* dq = &sq[w][s][d0];
    float* dk = &sk[w][s][d0];
    float* dv = &sv[w][s][d0];
    dq[0] = blo(qv.x); dq[1] = bhi(qv.x); dq[2] = blo(qv.y); dq[3] = bhi(qv.y);
    dq[4] = blo(qv.z); dq[5] = bhi(qv.z); dq[6] = blo(qv.w); dq[7] = bhi(qv.w);
    dk[0] = blo(kv.x); dk[1] = bhi(kv.x); dk[2] = blo(kv.y); dk[3] = bhi(kv.y);
    dk[4] = blo(kv.z); dk[5] = bhi(kv.z); dk[6] = blo(kv.w); dk[7] = bhi(kv.w);
    dv[0] = blo(vv.x); dv[1] = bhi(vv.x); dv[2] = blo(vv.y); dv[3] = bhi(vv.y);
    dv[4] = blo(vv.z); dv[5] = bhi(vv.z); dv[6] = blo(vv.w); dv[7] = bhi(vv.w);
  }
  __syncthreads();

  {  // scores + causal softmax: lane owns row sr, 4 cols t = tq*4+j
    const int sr = l & 15;
    const int tq = l >> 4;
    float sc[4] = {0.f, 0.f, 0.f, 0.f};
    for (int d = 0; d < 32; d += 4) {
      const float4 qv = *(const float4*)&sq[w][sr][d];
#pragma unroll
      for (int j = 0; j < 4; ++j) {
        const float4 kv = *(const float4*)&sk[w][tq * 4 + j][d];
        sc[j] += qv.x * kv.x + qv.y * kv.y + qv.z * kv.z + qv.w * kv.w;
      }
    }
    float mx = -1e30f;
#pragma unroll
    for (int j = 0; j < 4; ++j) {
      const int tt = tq * 4 + j;
      sc[j] = (tt > sr) ? -1e30f : sc[j] * 0.17677669529663687f;  // 1/sqrt(32)
      mx = fmaxf(mx, sc[j]);
    }
    mx = fmaxf(mx, __shfl_xor(mx, 16));
    mx = fmaxf(mx, __shfl_xor(mx, 32));
    float e[4]; float sm = 0.f;
#pragma unroll
    for (int j = 0; j < 4; ++j) { e[j] = expf(sc[j] - mx); sm += e[j]; }
    sm += __shfl_xor(sm, 16);
    sm += __shfl_xor(sm, 32);
#pragma unroll
    for (int j = 0; j < 4; ++j) sa[w][sr][tq * 4 + j] = e[j] / sm;
  }
  __syncthreads();

  {  // o[s,d] = sum_t a[s,t] * v[t,d]; pack 8 bf16 per lane (16B store)
    const int s  = l >> 2;
    const int d0 = (l & 3) * 8;
    float a0[4] = {0.f, 0.f, 0.f, 0.f}, a1[4] = {0.f, 0.f, 0.f, 0.f};
    for (int tt = 0; tt < 16; ++tt) {
      const float av = sa[w][s][tt];
      const float4 v0 = *(const float4*)&sv[w][tt][d0];
      const float4 v1 = *(const float4*)&sv[w][tt][d0 + 4];
      a0[0] = fmaf(av, v0.x, a0[0]); a0[1] = fmaf(av, v0.y, a0[1]);
      a0[2] = fmaf(av, v0.z, a0[2]); a0[3] = fmaf(av, v0.w, a0[3]);
      a1[0] = fmaf(av, v1.x, a1[0]); a1[1] = fmaf(av, v1.y, a1[1]);
      a1[2] = fmaf(av, v1.z, a1[2]); a1[3] = fmaf(av, v1.w, a1[3]);
    }
    const size_t ob = (size_t)(b * 16 + s) * 256 + hh * 32 + d0;
    uint4 p;
    p.x = pack2(a0[0], a0[1]); p.y = pack2(a0[2], a0[3]);
    p.z = pack2(a1[0], a1[1]); p.w = pack2(a1[2], a1[3]);
    *(uint4*)&o[ob] = p;
  }
}

// ---------------------------------------------------------------------------
// LayerNorm over E=256 (bf16 in/out, fp32 stats): one wave per row.
// ---------------------------------------------------------------------------
__launch_bounds__(256)
__global__ void ln_kernel(const short* __restrict__ xin, const float* __restrict__ g,
                          const float* __restrict__ bb, short* __restrict__ out) {
  const int w = threadIdx.x >> 6;
  const int l = threadIdx.x & 63;
  const size_t row = (size_t)blockIdx.x * 4 + w;
  const uint2 p = *(const uint2*)&xin[row * 256 + l * 4];
  float v0 = blo(p.x), v1 = bhi(p.x), v2 = blo(p.y), v3 = bhi(p.y);
  const float s  = wave_sum(v0 + v1 + v2 + v3);
  const float mu = s * (1.0f / 256.0f);
  float d0 = v0 - mu, d1 = v1 - mu, d2 = v2 - mu, d3 = v3 - mu;
  const float q   = wave_sum(d0 * d0 + d1 * d1 + d2 * d2 + d3 * d3);
  const float var = q * (1.0f / 256.0f);
  const float rs  = 1.0f / sqrtf(var + 1e-5f);
  const float4 gg = *(const float4*)&g[l * 4];
  const float4 bv = *(const float4*)&bb[l * 4];
  uint2 op;
  op.x = pack2(d0 * rs * gg.x + bv.x, d1 * rs * gg.y + bv.y);
  op.y = pack2(d2 * rs * gg.z + bv.z, d3 * rs * gg.w + bv.w);
  *(uint2*)&out[row * 256 + l * 4] = op;
}

// ---------------------------------------------------------------------------
// Final: out[b] = sum_s ( logits[s_local, x[b,s]] - logsumexp_v )
// logits chunk-local [MC, 512] fp32; one wave per b; 8 elements/lane.
// ---------------------------------------------------------------------------
__launch_bounds__(256)
__global__ void logprob_kernel(const float* __restrict__ logits, const int* __restrict__ x,
                               float* __restrict__ out, int b0) {
  const int w  = threadIdx.x >> 6;
  const int l  = threadIdx.x & 63;
  const int bl = blockIdx.x * 4 + w;
  const int b  = b0 + bl;
  float acc = 0.f;
  for (int s = 0; s < 16; ++s) {
    const float* row = logits + (size_t)(bl * 16 + s) * 512;
    float v[8];
#pragma unroll
    for (int i = 0; i < 8; ++i) v[i] = row[l + 64 * i];
    float mx = v[0];
#pragma unroll
    for (int i = 1; i < 8; ++i) mx = fmaxf(mx, v[i]);
    mx = wave_max(mx);
    float se = 0.f;
#pragma unroll
    for (int i = 0; i < 8; ++i) se += expf(v[i] - mx);
    se = wave_sum(se);
    const float lse = mx + logf(se);
    const float picked = row[x[b * 16 + s]];
    acc += picked - lse;
  }
  if (l == 0) out[b] = acc;
}

// ---------------------------------------------------------------------------
// Orchestration. Workspace: bf16 weights+c (14.2 MB) | cpr [B_,256] f32 (8 MB)
// | h [MC,256] bf16 | R [MC,1024] bf16 | X [MC,1024] bf16.
// logits (fp32 [MC,512]) aliases R exactly (same byte size). Adaptive BC.
// ---------------------------------------------------------------------------
extern "C" void kernel_launch(void* const* d_in, const int* in_sizes, int n_in,
                              void* d_out, int out_size, void* d_ws, size_t ws_size,
                              hipStream_t stream) {
  const int*   x       = (const int*)  d_in[0];
  const float* c       = (const float*)d_in[1];
  const float* x_emb   = (const float*)d_in[2];
  const float* pos_emb = (const float*)d_in[3];
  const float* c_W     = (const float*)d_in[4];
  const float* c_b     = (const float*)d_in[5];
  const float* Wqkv    = (const float*)d_in[6];
  const float* bqkv    = (const float*)d_in[7];
  const float* Wo      = (const float*)d_in[8];
  const float* bo      = (const float*)d_in[9];
  const float* ln1_g   = (const float*)d_in[10];
  const float* ln1_b   = (const float*)d_in[11];
  const float* W1      = (const float*)d_in[12];
  const float* b1      = (const float*)d_in[13];
  const float* W2      = (const float*)d_in[14];
  const float* b2      = (const float*)d_in[15];
  const float* ln2_g   = (const float*)d_in[16];
  const float* ln2_b   = (const float*)d_in[17];
  const float* mW0     = (const float*)d_in[18];
  const float* mb0     = (const float*)d_in[19];
  const float* mW1     = (const float*)d_in[20];
  const float* mb1     = (const float*)d_in[21];
  const float* mW2     = (const float*)d_in[22];
  const float* mb2     = (const float*)d_in[23];
  float* out = (float*)d_out;

  // bf16 region element counts
  const size_t nWqkv = (size_t)L_ * 768 * 256;
  const size_t nWo   = (size_t)L_ * 256 * 256;
  const size_t nW1   = (size_t)L_ * 1024 * 256;
  const size_t nW2   = (size_t)L_ * 256 * 1024;
  const size_t nmW0  = (size_t)U_ * E_;
  const size_t nmW1  = (size_t)U_ * U_;
  const size_t nmW2  = (size_t)V_ * U_;
  const size_t ncW   = (size_t)E_ * DC_;
  const size_t nC    = (size_t)B_ * DC_;
  const size_t WBF   = nWqkv + nWo + nW1 + nW2 + nmW0 + nmW1 + nmW2 + ncW + nC;

  short* bWqkv = (short*)d_ws;
  short* bWo   = bWqkv + nWqkv;
  short* bW1   = bWo   + nWo;
  short* bW2   = bW1   + nW1;
  short* bmW0  = bW2   + nW2;
  short* bmW1  = bmW0  + nmW0;
  short* bmW2  = bmW1  + nmW1;
  short* bcW   = bmW2  + nmW2;
  short* bC    = bcW   + ncW;

  // Pick largest chunk (rows) that fits after weights + cpr.
  const size_t fixed_bytes = WBF * 2 + (size_t)B_ * 256 * 4;
  int BC = 0;
  for (int bc = B_; bc >= 128; bc >>= 1) {
    const size_t need = fixed_bytes + (size_t)bc * 16 * 2304 * 2;  // bf16 activations
    if (need <= ws_size) { BC = bc; break; }
  }
  if (BC == 0) return;  // fail visibly via graph node count
  const int MC = BC * 16;
  const int NCHUNK = B_ / BC;

  float* cpr = (float*)((char*)d_ws + WBF * 2);
  short* h   = (short*)(cpr + (size_t)B_ * 256);
  short* R   = h + (size_t)MC * 256;
  short* X   = R + (size_t)MC * 1024;
  float* logitsF = (float*)R;  // [MC,512] fp32 aliases R's bytes exactly

  const dim3 blk(256);

  // Convert weights (+ c input) fp32 -> bf16 each call (d_ws is re-poisoned).
  w2bf_kernel<<<dim3(nWqkv / 1024), blk, 0, stream>>>(Wqkv, bWqkv);
  w2bf_kernel<<<dim3(nWo   / 1024), blk, 0, stream>>>(Wo,   bWo);
  w2bf_kernel<<<dim3(nW1   / 1024), blk, 0, stream>>>(W1,   bW1);
  w2bf_kernel<<<dim3(nW2   / 1024), blk, 0, stream>>>(W2,   bW2);
  w2bf_kernel<<<dim3(nmW0  / 1024), blk, 0, stream>>>(mW0,  bmW0);
  w2bf_kernel<<<dim3(nmW1  / 1024), blk, 0, stream>>>(mW1,  bmW1);
  w2bf_kernel<<<dim3(nmW2  / 1024), blk, 0, stream>>>(mW2,  bmW2);
  w2bf_kernel<<<dim3(ncW   / 1024), blk, 0, stream>>>(c_W,  bcW);
  w2bf_kernel<<<dim3(nC    / 1024), blk, 0, stream>>>(c,    bC);

  // cproj = c @ c_W^T + c_b   [B_,256] fp32, K=64  (whole batch, once)
  gemm_bf16_kernel<0, false, true><<<dim3((B_ / 128) * (E_ / 128)), blk, 0, stream>>>(
      bC, bcW, c_b, nullptr, cpr, B_, E_, DC_);

  for (int ci = 0; ci < NCHUNK; ++ci) {
    const int b0 = ci * BC;
    embed_kernel<<<dim3((MC * 64) / 256), blk, 0, stream>>>(x, x_emb, pos_emb, cpr, h, b0);

    for (int l = 0; l < L_; ++l) {
      // qkv = h @ Wqkv^T + bqkv   [MC,768] bf16, K=256  -> R
      gemm_bf16_kernel<0, false, false><<<dim3((MC / 128) * (768 / 128)), blk, 0, stream>>>(
          h, bWqkv + (size_t)l * 768 * 256, bqkv + (size_t)l * 768, nullptr, R, MC, 768, 256);
      // o = attention(qkv)   [MC,256] bf16  -> X
      attn_kernel<<<dim3(BC * 2), blk, 0, stream>>>(R, X);
      // preLN = o @ Wo^T + bo + h   [MC,256] bf16, K=256  -> R
      gemm_bf16_kernel<0, true, false><<<dim3((MC / 128) * (E_ / 128)), blk, 0, stream>>>(
          X, bWo + (size_t)l * 256 * 256, bo + (size_t)l * 256, h, R, MC, 256, 256);
      // h = LN1(preLN)
      ln_kernel<<<dim3(MC / 4), blk, 0, stream>>>(R, ln1_g + (size_t)l * 256,
                                                  ln1_b + (size_t)l * 256, h);
      // f = gelu(h @ W1^T + b1)   [MC,1024] bf16, K=256  -> R
      gemm_bf16_kernel<1, false, false><<<dim3((MC / 128) * (FF_ / 128)), blk, 0, stream>>>(
          h, bW1 + (size_t)l * 1024 * 256, b1 + (size_t)l * 1024, nullptr, R, MC, 1024, 256);
      // preLN = f @ W2^T + b2 + h   [MC,256] bf16, K=1024  -> X
      gemm_bf16_kernel<0, true, false><<<dim3((MC / 128) * (E_ / 128)), blk, 0, stream>>>(
          R, bW2 + (size_t)l * 256 * 1024, b2 + (size_t)l * 256, h, X, MC, 256, 1024);
      // h = LN2(preLN)
      ln_kernel<<<dim3(MC / 4), blk, 0, stream>>>(X, ln2_g + (size_t)l * 256,
                                                  ln2_b + (size_t)l * 256, h);
    }

    // Head MLP (chunk-local)
    gemm_bf16_kernel<2, false, false><<<dim3((MC / 128) * (U_ / 128)), blk, 0, stream>>>(
        h, bmW0, mb0, nullptr, R, MC, U_, E_);           // z0 = relu(.) -> R (bf16)
    gemm_bf16_kernel<2, false, false><<<dim3((MC / 128) * (U_ / 128)), blk, 0, stream>>>(
        R, bmW1, mb1, nullptr, X, MC, U_, U_);           // z1 = relu(.) -> X (bf16)
    gemm_bf16_kernel<0, false, true><<<dim3((MC / 128) * (V_ / 128)), blk, 0, stream>>>(
        X, bmW2, mb2, nullptr, logitsF, MC, V_, U_);     // logits -> R bytes (fp32)

    logprob_kernel<<<dim3(BC / 4), blk, 0, stream>>>(logitsF, x, out, b0);
  }
}

// Round 6
// 5241.666 us; speedup vs baseline: 4.6100x; 1.3174x over previous
//
#include <hip/hip_runtime.h>
#include <hip/hip_bf16.h>
#include <math.h>

// Problem constants (DiscreteTransformer)
#define B_  8192
#define S_  16
#define E_  256
#define H_  8
#define FF_ 1024
#define L_  6
#define V_  512
#define U_  1024
#define DC_ 64
#define M_  (B_ * S_)     // 131072 tokens

typedef __attribute__((ext_vector_type(8))) short short8;   // 8 bf16 (4 VGPRs)
typedef __attribute__((ext_vector_type(4))) float f32x4;

// ---------------------------------------------------------------------------
// Wave (64-lane) reductions
// ---------------------------------------------------------------------------
__device__ __forceinline__ float wave_sum(float v) {
#pragma unroll
  for (int off = 32; off >= 1; off >>= 1) v += __shfl_xor(v, off);
  return v;
}
__device__ __forceinline__ float wave_max(float v) {
#pragma unroll
  for (int off = 32; off >= 1; off >>= 1) v = fmaxf(v, __shfl_xor(v, off));
  return v;
}

// bf16 <-> fp32 helpers (bf16 stored as short; RNE rounding on the way down)
__device__ __forceinline__ unsigned bfround(float f) {
  unsigned u = __builtin_bit_cast(unsigned, f);
  return (u + 0x7FFFu + ((u >> 16) & 1u)) >> 16;
}
__device__ __forceinline__ unsigned pack2(float lo, float hi) {
  return bfround(lo) | (bfround(hi) << 16);
}
__device__ __forceinline__ float b2f(short s) {
  return __builtin_bit_cast(float, (unsigned)(unsigned short)s << 16);
}
__device__ __forceinline__ float blo(unsigned u) { return __builtin_bit_cast(float, u << 16); }
__device__ __forceinline__ float bhi(unsigned u) { return __builtin_bit_cast(float, u & 0xFFFF0000u); }

// Async global -> LDS, 16 B per lane (global src per-lane, LDS dest linear).
__device__ __forceinline__ void gload_lds16(const void* g, void* l) {
  __builtin_amdgcn_global_load_lds(
      (const __attribute__((address_space(1))) void*)g,
      (__attribute__((address_space(3))) void*)l, 16, 0, 0);
}

// ---------------------------------------------------------------------------
// fp32 -> bf16 bulk conversion (exact grid; n % 1024 == 0)
// ---------------------------------------------------------------------------
__global__ void w2bf_kernel(const float* __restrict__ src, short* __restrict__ dst) {
  const int i = blockIdx.x * 256 + threadIdx.x;  // over n/4
  const float4 v = ((const float4*)src)[i];
  uint2 p;
  p.x = pack2(v.x, v.y);
  p.y = pack2(v.z, v.w);
  ((uint2*)dst)[i] = p;
}

// ---------------------------------------------------------------------------
// bf16-MFMA GEMM: C[M,N] = act(A[M,K] @ W[N,K]^T + bias[N] (+ res[M,N]))
// A,W bf16 row-major K-contiguous. fp32 accum via v_mfma_f32_16x16x32_bf16.
// Tile 128x128xBK64; 256 threads = 4 waves (2x2); 4x4 16x16 frags/wave.
//
// Staging: __builtin_amdgcn_global_load_lds width 16 into LINEAR LDS
// [128][64] shorts. LDS dest is base+lane*16 (linear), so the XOR bank-
// swizzle is applied on the GLOBAL source address and again on the ds_read
// address (both-sides rule): physical colshorts = logical ^ 8*(row&7).
// Bank check: quad = kg^(lr&7) -> 8 lanes/quad = conflict-free b128 floor.
// Requires M%128==0, N%128==0, K%64==0. ACT: 0=none,1=gelu(erf),2=relu.
// OUTF32: write fp32 C (for cproj / logits), else bf16.
// ---------------------------------------------------------------------------
template <int ACT, bool RES, bool OUTF32>
__launch_bounds__(256, 2)
__global__ void gemm_bf16_kernel(const short* __restrict__ A, const short* __restrict__ W,
                                 const float* __restrict__ bias, const short* __restrict__ res,
                                 void* __restrict__ Cv, int M, int N, int K) {
  __shared__ __align__(16) short As[128 * 64];
  __shared__ __align__(16) short Ws[128 * 64];
  const int t  = threadIdx.x;
  const int w  = t >> 6;          // wave 0..3
  const int l  = t & 63;
  const int wr = w >> 1;          // wave row (2)
  const int wc = w & 1;           // wave col (2)
  const int lr = l & 15;          // fragment row lane
  const int kg = l >> 4;          // k-group 0..3
  const int nbn = N / 128;
  const int bm = blockIdx.x / nbn;  // consecutive blocks sweep bn -> A panel L2 reuse
  const int bn = blockIdx.x % nbn;
  const int m0 = bm * 128, n0 = bn * 128;

  f32x4 acc[4][4] = {};

  // staging geometry: 16 chunks/operand (8 rows x 64 shorts = 1024 B each);
  // wave w stages chunks w*4..w*4+3. lane: row-in-chunk rg, swizzled col cs.
  const int rg = l >> 3;                      // 0..7
  const int cs = ((l & 7) ^ rg) * 8;          // pre-swizzled source col (shorts)
  const int swz = (lr & 7) * 8;               // read-side XOR (shorts)

  for (int k0 = 0; k0 < K; k0 += 64) {
    const short* Ab = &A[(size_t)m0 * K + k0 + cs];
    const short* Wb = &W[(size_t)n0 * K + k0 + cs];
#pragma unroll
    for (int q = 0; q < 4; ++q) {
      const int i = w * 4 + q;
      const int row = i * 8 + rg;
      gload_lds16(Ab + (size_t)row * K, &As[i * 512]);
      gload_lds16(Wb + (size_t)row * K, &Ws[i * 512]);
    }
    __syncthreads();  // compiler drains vmcnt(0) before s_barrier

#pragma unroll
    for (int kk = 0; kk < 64; kk += 32) {
      short8 af[4], bf[4];
#pragma unroll
      for (int mi = 0; mi < 4; ++mi)
        af[mi] = *(const short8*)&As[(wr * 64 + mi * 16 + lr) * 64 + ((kk + kg * 8) ^ swz)];
#pragma unroll
      for (int ni = 0; ni < 4; ++ni)
        bf[ni] = *(const short8*)&Ws[(wc * 64 + ni * 16 + lr) * 64 + ((kk + kg * 8) ^ swz)];
#pragma unroll
      for (int mi = 0; mi < 4; ++mi)
#pragma unroll
        for (int ni = 0; ni < 4; ++ni)
          acc[mi][ni] = __builtin_amdgcn_mfma_f32_16x16x32_bf16(af[mi], bf[ni], acc[mi][ni], 0, 0, 0);
    }
    __syncthreads();
  }

  float* Cf = (float*)Cv;
  short* Cb = (short*)Cv;
  // epilogue: C/D layout col=l&15, row=(l>>4)*4+j  [m89-verified]
#pragma unroll
  for (int ni = 0; ni < 4; ++ni) {
    const int n = n0 + wc * 64 + ni * 16 + lr;
    const float bv = bias[n];
#pragma unroll
    for (int mi = 0; mi < 4; ++mi) {
      const int mbase = m0 + wr * 64 + mi * 16 + kg * 4;
#pragma unroll
      for (int j = 0; j < 4; ++j) {
        float z = acc[mi][ni][j] + bv;
        const size_t off = (size_t)(mbase + j) * N + n;
        if (RES) z += b2f(res[off]);
        if (ACT == 1) z = 0.5f * z * (1.0f + erff(z * 0.70710678118654752f));
        if (ACT == 2) z = fmaxf(z, 0.0f);
        if (OUTF32) Cf[off] = z;
        else        Cb[off] = (short)bfround(z);
      }
    }
  }
}

// ---------------------------------------------------------------------------
// Embedding (chunk-local bf16 h): h[t,:] = (s==0?0:x_emb[x[b,s-1]]) + pos_emb[s]
//                                         + cproj[b],  b = b0 + t/16, s = t%16
// ---------------------------------------------------------------------------
__global__ void embed_kernel(const int* __restrict__ x, const float* __restrict__ x_emb,
                             const float* __restrict__ pos_emb, const float* __restrict__ cproj,
                             short* __restrict__ h, int b0) {
  const int idx = blockIdx.x * 256 + threadIdx.x;
  const int e4 = idx & 63;
  const int s  = (idx >> 6) & 15;
  const int b  = b0 + (idx >> 10);
  const float4 pe = ((const float4*)pos_emb)[s * 64 + e4];
  const float4 cp = ((const float4*)cproj)[b * 64 + e4];
  float4 v;
  v.x = pe.x + cp.x; v.y = pe.y + cp.y; v.z = pe.z + cp.z; v.w = pe.w + cp.w;
  if (s > 0) {
    const int tok = x[b * 16 + s - 1];
    const float4 xe = ((const float4*)x_emb)[tok * 64 + e4];
    v.x += xe.x; v.y += xe.y; v.z += xe.z; v.w += xe.w;
  }
  uint2 p;
  p.x = pack2(v.x, v.y);
  p.y = pack2(v.z, v.w);
  ((uint2*)h)[idx] = p;
}

// ---------------------------------------------------------------------------
// Attention (chunk-local, bf16 I/O): per (b_local, head) on one wave. S=16, dh=32.
// qkv [MC,768] bf16: 0..255 q, 256..511 k, 512..767 v; head hh at hh*32.
// ---------------------------------------------------------------------------
__launch_bounds__(256)
__global__ void attn_kernel(const short* __restrict__ qkv, short* __restrict__ o) {
  __shared__ __align__(16) float sq[4][16][36];
  __shared__ __align__(16) float sk[4][16][36];
  __shared__ __align__(16) float sv[4][16][36];
  __shared__ float sa[4][16][17];
  const int w   = threadIdx.x >> 6;
  const int l   = threadIdx.x & 63;
  const int gid = blockIdx.x * 4 + w;   // = b_local*8 + head
  const int b   = gid >> 3;
  const int hh  = gid & 7;

  {  // cooperative load+convert: 16 rows x 32 d, 4 lanes/row, 8 bf16 per seg
    const int s  = l >> 2;
    const int d0 = (l & 3) * 8;
    const size_t base = (size_t)(b * 16 + s) * 768 + hh * 32 + d0;
    const uint4 qv = *(const uint4*)&qkv[base];
    const uint4 kv = *(const uint4*)&qkv[base + 256];
    const uint4 vv = *(const uint4*)&qkv[base + 512];
    float* dq = &sq[w][s][d0];
    float* dk = &sk[w][s][d0];
    float* dv = &sv[w][s][d0];
    dq[0] = blo(qv.x); dq[1] = bhi(qv.x); dq[2] = blo(qv.y); dq[3] = bhi(qv.y);
    dq[4] = blo(qv.z); dq[5] = bhi(qv.z); dq[6] = blo(qv.w); dq[7] = bhi(qv.w);
    dk[0] = blo(kv.x); dk[1] = bhi(kv.x); dk[2] = blo(kv.y); dk[3] = bhi(kv.y);
    dk[4] = blo(kv.z); dk[5] = bhi(kv.z); dk[6] = blo(kv.w); dk[7] = bhi(kv.w);
    dv[0] = blo(vv.x); dv[1] = bhi(vv.x); dv[2] = blo(vv.y); dv[3] = bhi(vv.y);
    dv[4] = blo(vv.z); dv[5] = bhi(vv.z); dv[6] = blo(vv.w); dv[7] = bhi(vv.w);
  }
  __syncthreads();

  {  // scores + causal softmax: lane owns row sr, 4 cols t = tq*4+j
    const int sr = l & 15;
    const int tq = l >> 4;
    float sc[4] = {0.f, 0.f, 0.f, 0.f};
    for (int d = 0; d < 32; d += 4) {
      const float4 qv = *(const float4*)&sq[w][sr][d];
#pragma unroll
      for (int j = 0; j < 4; ++j) {
        const float4 kv = *(const float4*)&sk[w][tq * 4 + j][d];
        sc[j] += qv.x * kv.x + qv.y * kv.y + qv.z * kv.z + qv.w * kv.w;
      }
    }
    float mx = -1e30f;
#pragma unroll
    for (int j = 0; j < 4; ++j) {
      const int tt = tq * 4 + j;
      sc[j] = (tt > sr) ? -1e30f : sc[j] * 0.17677669529663687f;  // 1/sqrt(32)
      mx = fmaxf(mx, sc[j]);
    }
    mx = fmaxf(mx, __shfl_xor(mx, 16));
    mx = fmaxf(mx, __shfl_xor(mx, 32));
    float e[4]; float sm = 0.f;
#pragma unroll
    for (int j = 0; j < 4; ++j) { e[j] = expf(sc[j] - mx); sm += e[j]; }
    sm += __shfl_xor(sm, 16);
    sm += __shfl_xor(sm, 32);
#pragma unroll
    for (int j = 0; j < 4; ++j) sa[w][sr][tq * 4 + j] = e[j] / sm;
  }
  __syncthreads();

  {  // o[s,d] = sum_t a[s,t] * v[t,d]; pack 8 bf16 per lane (16B store)
    const int s  = l >> 2;
    const int d0 = (l & 3) * 8;
    float a0[4] = {0.f, 0.f, 0.f, 0.f}, a1[4] = {0.f, 0.f, 0.f, 0.f};
    for (int tt = 0; tt < 16; ++tt) {
      const float av = sa[w][s][tt];
      const float4 v0 = *(const float4*)&sv[w][tt][d0];
      const float4 v1 = *(const float4*)&sv[w][tt][d0 + 4];
      a0[0] = fmaf(av, v0.x, a0[0]); a0[1] = fmaf(av, v0.y, a0[1]);
      a0[2] = fmaf(av, v0.z, a0[2]); a0[3] = fmaf(av, v0.w, a0[3]);
      a1[0] = fmaf(av, v1.x, a1[0]); a1[1] = fmaf(av, v1.y, a1[1]);
      a1[2] = fmaf(av, v1.z, a1[2]); a1[3] = fmaf(av, v1.w, a1[3]);
    }
    const size_t ob = (size_t)(b * 16 + s) * 256 + hh * 32 + d0;
    uint4 p;
    p.x = pack2(a0[0], a0[1]); p.y = pack2(a0[2], a0[3]);
    p.z = pack2(a1[0], a1[1]); p.w = pack2(a1[2], a1[3]);
    *(uint4*)&o[ob] = p;
  }
}

// ---------------------------------------------------------------------------
// LayerNorm over E=256 (bf16 in/out, fp32 stats): one wave per row.
// Single reduction pass: sum and sumsq reduced concurrently (ILP), var via
// E[x^2]-mu^2 (fine at fp32 for LN-scale values; bf16 output dominates error).
// ---------------------------------------------------------------------------
__launch_bounds__(256)
__global__ void ln_kernel(const short* __restrict__ xin, const float* __restrict__ g,
                          const float* __restrict__ bb, short* __restrict__ out) {
  const int w = threadIdx.x >> 6;
  const int l = threadIdx.x & 63;
  const size_t row = (size_t)blockIdx.x * 4 + w;
  const uint2 p = *(const uint2*)&xin[row * 256 + l * 4];
  float v0 = blo(p.x), v1 = bhi(p.x), v2 = blo(p.y), v3 = bhi(p.y);
  float s1 = v0 + v1 + v2 + v3;
  float s2 = fmaf(v0, v0, fmaf(v1, v1, fmaf(v2, v2, v3 * v3)));
#pragma unroll
  for (int off = 32; off >= 1; off >>= 1) {
    s1 += __shfl_xor(s1, off);
    s2 += __shfl_xor(s2, off);
  }
  const float mu  = s1 * (1.0f / 256.0f);
  const float var = s2 * (1.0f / 256.0f) - mu * mu;
  const float rs  = 1.0f / sqrtf(var + 1e-5f);
  const float4 gg = *(const float4*)&g[l * 4];
  const float4 bv = *(const float4*)&bb[l * 4];
  uint2 op;
  op.x = pack2((v0 - mu) * rs * gg.x + bv.x, (v1 - mu) * rs * gg.y + bv.y);
  op.y = pack2((v2 - mu) * rs * gg.z + bv.z, (v3 - mu) * rs * gg.w + bv.w);
  *(uint2*)&out[row * 256 + l * 4] = op;
}

// ---------------------------------------------------------------------------
// Final: out[b] = sum_s ( logits[s_local, x[b,s]] - logsumexp_v )
// logits chunk-local [MC, 512] fp32; one wave per b; 8 elements/lane.
// ---------------------------------------------------------------------------
__launch_bounds__(256)
__global__ void logprob_kernel(const float* __restrict__ logits, const int* __restrict__ x,
                               float* __restrict__ out, int b0) {
  const int w  = threadIdx.x >> 6;
  const int l  = threadIdx.x & 63;
  const int bl = blockIdx.x * 4 + w;
  const int b  = b0 + bl;
  float acc = 0.f;
  for (int s = 0; s < 16; ++s) {
    const float* row = logits + (size_t)(bl * 16 + s) * 512;
    float v[8];
#pragma unroll
    for (int i = 0; i < 8; ++i) v[i] = row[l + 64 * i];
    float mx = v[0];
#pragma unroll
    for (int i = 1; i < 8; ++i) mx = fmaxf(mx, v[i]);
    mx = wave_max(mx);
    float se = 0.f;
#pragma unroll
    for (int i = 0; i < 8; ++i) se += expf(v[i] - mx);
    se = wave_sum(se);
    const float lse = mx + logf(se);
    const float picked = row[x[b * 16 + s]];
    acc += picked - lse;
  }
  if (l == 0) out[b] = acc;
}

// ---------------------------------------------------------------------------
// Orchestration. Workspace: bf16 weights+c (14.2 MB) | cpr [B_,256] f32 (8 MB)
// | h [MC,256] bf16 | R [MC,1024] bf16 | X [MC,1024] bf16.
// logits (fp32 [MC,512]) aliases R exactly (same byte size). Adaptive BC.
// ---------------------------------------------------------------------------
extern "C" void kernel_launch(void* const* d_in, const int* in_sizes, int n_in,
                              void* d_out, int out_size, void* d_ws, size_t ws_size,
                              hipStream_t stream) {
  const int*   x       = (const int*)  d_in[0];
  const float* c       = (const float*)d_in[1];
  const float* x_emb   = (const float*)d_in[2];
  const float* pos_emb = (const float*)d_in[3];
  const float* c_W     = (const float*)d_in[4];
  const float* c_b     = (const float*)d_in[5];
  const float* Wqkv    = (const float*)d_in[6];
  const float* bqkv    = (const float*)d_in[7];
  const float* Wo      = (const float*)d_in[8];
  const float* bo      = (const float*)d_in[9];
  const float* ln1_g   = (const float*)d_in[10];
  const float* ln1_b   = (const float*)d_in[11];
  const float* W1      = (const float*)d_in[12];
  const float* b1      = (const float*)d_in[13];
  const float* W2      = (const float*)d_in[14];
  const float* b2      = (const float*)d_in[15];
  const float* ln2_g   = (const float*)d_in[16];
  const float* ln2_b   = (const float*)d_in[17];
  const float* mW0     = (const float*)d_in[18];
  const float* mb0     = (const float*)d_in[19];
  const float* mW1     = (const float*)d_in[20];
  const float* mb1     = (const float*)d_in[21];
  const float* mW2     = (const float*)d_in[22];
  const float* mb2     = (const float*)d_in[23];
  float* out = (float*)d_out;

  // bf16 region element counts
  const size_t nWqkv = (size_t)L_ * 768 * 256;
  const size_t nWo   = (size_t)L_ * 256 * 256;
  const size_t nW1   = (size_t)L_ * 1024 * 256;
  const size_t nW2   = (size_t)L_ * 256 * 1024;
  const size_t nmW0  = (size_t)U_ * E_;
  const size_t nmW1  = (size_t)U_ * U_;
  const size_t nmW2  = (size_t)V_ * U_;
  const size_t ncW   = (size_t)E_ * DC_;
  const size_t nC    = (size_t)B_ * DC_;
  const size_t WBF   = nWqkv + nWo + nW1 + nW2 + nmW0 + nmW1 + nmW2 + ncW + nC;

  short* bWqkv = (short*)d_ws;
  short* bWo   = bWqkv + nWqkv;
  short* bW1   = bWo   + nWo;
  short* bW2   = bW1   + nW1;
  short* bmW0  = bW2   + nW2;
  short* bmW1  = bmW0  + nmW0;
  short* bmW2  = bmW1  + nmW1;
  short* bcW   = bmW2  + nmW2;
  short* bC    = bcW   + ncW;

  // Pick largest chunk (rows) that fits after weights + cpr.
  const size_t fixed_bytes = WBF * 2 + (size_t)B_ * 256 * 4;
  int BC = 0;
  for (int bc = B_; bc >= 128; bc >>= 1) {
    const size_t need = fixed_bytes + (size_t)bc * 16 * 2304 * 2;  // bf16 activations
    if (need <= ws_size) { BC = bc; break; }
  }
  if (BC == 0) return;  // fail visibly via graph node count
  const int MC = BC * 16;
  const int NCHUNK = B_ / BC;

  float* cpr = (float*)((char*)d_ws + WBF * 2);
  short* h   = (short*)(cpr + (size_t)B_ * 256);
  short* R   = h + (size_t)MC * 256;
  short* X   = R + (size_t)MC * 1024;
  float* logitsF = (float*)R;  // [MC,512] fp32 aliases R's bytes exactly

  const dim3 blk(256);

  // Convert weights (+ c input) fp32 -> bf16 each call (d_ws is re-poisoned).
  w2bf_kernel<<<dim3(nWqkv / 1024), blk, 0, stream>>>(Wqkv, bWqkv);
  w2bf_kernel<<<dim3(nWo   / 1024), blk, 0, stream>>>(Wo,   bWo);
  w2bf_kernel<<<dim3(nW1   / 1024), blk, 0, stream>>>(W1,   bW1);
  w2bf_kernel<<<dim3(nW2   / 1024), blk, 0, stream>>>(W2,   bW2);
  w2bf_kernel<<<dim3(nmW0  / 1024), blk, 0, stream>>>(mW0,  bmW0);
  w2bf_kernel<<<dim3(nmW1  / 1024), blk, 0, stream>>>(mW1,  bmW1);
  w2bf_kernel<<<dim3(nmW2  / 1024), blk, 0, stream>>>(mW2,  bmW2);
  w2bf_kernel<<<dim3(ncW   / 1024), blk, 0, stream>>>(c_W,  bcW);
  w2bf_kernel<<<dim3(nC    / 1024), blk, 0, stream>>>(c,    bC);

  // cproj = c @ c_W^T + c_b   [B_,256] fp32, K=64  (whole batch, once)
  gemm_bf16_kernel<0, false, true><<<dim3((B_ / 128) * (E_ / 128)), blk, 0, stream>>>(
      bC, bcW, c_b, nullptr, cpr, B_, E_, DC_);

  for (int ci = 0; ci < NCHUNK; ++ci) {
    const int b0 = ci * BC;
    embed_kernel<<<dim3((MC * 64) / 256), blk, 0, stream>>>(x, x_emb, pos_emb, cpr, h, b0);

    for (int l = 0; l < L_; ++l) {
      // qkv = h @ Wqkv^T + bqkv   [MC,768] bf16, K=256  -> R
      gemm_bf16_kernel<0, false, false><<<dim3((MC / 128) * (768 / 128)), blk, 0, stream>>>(
          h, bWqkv + (size_t)l * 768 * 256, bqkv + (size_t)l * 768, nullptr, R, MC, 768, 256);
      // o = attention(qkv)   [MC,256] bf16  -> X
      attn_kernel<<<dim3(BC * 2), blk, 0, stream>>>(R, X);
      // preLN = o @ Wo^T + bo + h   [MC,256] bf16, K=256  -> R
      gemm_bf16_kernel<0, true, false><<<dim3((MC / 128) * (E_ / 128)), blk, 0, stream>>>(
          X, bWo + (size_t)l * 256 * 256, bo + (size_t)l * 256, h, R, MC, 256, 256);
      // h = LN1(preLN)
      ln_kernel<<<dim3(MC / 4), blk, 0, stream>>>(R, ln1_g + (size_t)l * 256,
                                                  ln1_b + (size_t)l * 256, h);
      // f = gelu(h @ W1^T + b1)   [MC,1024] bf16, K=256  -> R
      gemm_bf16_kernel<1, false, false><<<dim3((MC / 128) * (FF_ / 128)), blk, 0, stream>>>(
          h, bW1 + (size_t)l * 1024 * 256, b1 + (size_t)l * 1024, nullptr, R, MC, 1024, 256);
      // preLN = f @ W2^T + b2 + h   [MC,256] bf16, K=1024  -> X
      gemm_bf16_kernel<0, true, false><<<dim3((MC / 128) * (E_ / 128)), blk, 0, stream>>>(
          R, bW2 + (size_t)l * 256 * 1024, b2 + (size_t)l * 256, h, X, MC, 256, 1024);
      // h = LN2(preLN)
      ln_kernel<<<dim3(MC / 4), blk, 0, stream>>>(X, ln2_g + (size_t)l * 256,
                                                  ln2_b + (size_t)l * 256, h);
    }

    // Head MLP (chunk-local)
    gemm_bf16_kernel<2, false, false><<<dim3((MC / 128) * (U_ / 128)), blk, 0, stream>>>(
        h, bmW0, mb0, nullptr, R, MC, U_, E_);           // z0 = relu(.) -> R (bf16)
    gemm_bf16_kernel<2, false, false><<<dim3((MC / 128) * (U_ / 128)), blk, 0, stream>>>(
        R, bmW1, mb1, nullptr, X, MC, U_, U_);           // z1 = relu(.) -> X (bf16)
    gemm_bf16_kernel<0, false, true><<<dim3((MC / 128) * (V_ / 128)), blk, 0, stream>>>(
        X, bmW2, mb2, nullptr, logitsF, MC, V_, U_);     // logits -> R bytes (fp32)

    logprob_kernel<<<dim3(BC / 4), blk, 0, stream>>>(logitsF, x, out, b0);
  }
}

// Round 8
// 3840.972 us; speedup vs baseline: 6.2912x; 1.3647x over previous
//
#include <hip/hip_runtime.h>
#include <hip/hip_bf16.h>
#include <math.h>

// Problem constants (DiscreteTransformer)
#define B_  8192
#define S_  16
#define E_  256
#define H_  8
#define FF_ 1024
#define L_  6
#define V_  512
#define U_  1024
#define DC_ 64
#define M_  (B_ * S_)     // 131072 tokens

typedef __attribute__((ext_vector_type(8))) short short8;   // 8 bf16 (4 VGPRs)
typedef __attribute__((ext_vector_type(4))) float f32x4;

// ---------------------------------------------------------------------------
// Wave (64-lane) reductions
// ---------------------------------------------------------------------------
__device__ __forceinline__ float wave_sum(float v) {
#pragma unroll
  for (int off = 32; off >= 1; off >>= 1) v += __shfl_xor(v, off);
  return v;
}
__device__ __forceinline__ float wave_max(float v) {
#pragma unroll
  for (int off = 32; off >= 1; off >>= 1) v = fmaxf(v, __shfl_xor(v, off));
  return v;
}

// bf16 <-> fp32 helpers (bf16 stored as short; RNE rounding on the way down)
__device__ __forceinline__ unsigned bfround(float f) {
  unsigned u = __builtin_bit_cast(unsigned, f);
  return (u + 0x7FFFu + ((u >> 16) & 1u)) >> 16;
}
__device__ __forceinline__ unsigned pack2(float lo, float hi) {
  return bfround(lo) | (bfround(hi) << 16);
}
__device__ __forceinline__ float b2f(short s) {
  return __builtin_bit_cast(float, (unsigned)(unsigned short)s << 16);
}
__device__ __forceinline__ float blo(unsigned u) { return __builtin_bit_cast(float, u << 16); }
__device__ __forceinline__ float bhi(unsigned u) { return __builtin_bit_cast(float, u & 0xFFFF0000u); }

// Async global -> LDS, 16 B per lane (global src per-lane, LDS dest linear).
__device__ __forceinline__ void gload_lds16(const void* g, void* l) {
  __builtin_amdgcn_global_load_lds(
      (const __attribute__((address_space(1))) void*)g,
      (__attribute__((address_space(3))) void*)l, 16, 0, 0);
}

// Bijective XCD-aware block swizzle (requires nblk % 8 == 0; all our grids are).
__device__ __forceinline__ int xcd_swz(int bid, int nblk) {
  return (bid & 7) * (nblk >> 3) + (bid >> 3);
}

// ---------------------------------------------------------------------------
// fp32 -> bf16 bulk conversion (exact grid; n % 1024 == 0)
// ---------------------------------------------------------------------------
__global__ void w2bf_kernel(const float* __restrict__ src, short* __restrict__ dst) {
  const int i = blockIdx.x * 256 + threadIdx.x;  // over n/4
  const float4 v = ((const float4*)src)[i];
  uint2 p;
  p.x = pack2(v.x, v.y);
  p.y = pack2(v.z, v.w);
  ((uint2*)dst)[i] = p;
}

// ---------------------------------------------------------------------------
// bf16-MFMA GEMM: C[M,N] = act(A[M,K] @ W[N,K]^T + bias[N] (+ res[M,N]))
// A,W bf16 row-major K-contiguous. fp32 accum via v_mfma_f32_16x16x32_bf16.
// Tile 128x128xBK64; 256 threads = 4 waves (2x2); 4x4 16x16 frags/wave.
// Staging: global_load_lds width 16 into linear LDS, XOR swizzle applied on
// BOTH the global source and the ds_read address (rule #21). Conflict-free
// (measured: SQ_LDS_BANK_CONFLICT = 0). XCD-aware block swizzle for L2.
// Requires M%128==0, N%128==0, K%64==0. ACT: 0=none,1=gelu(erf),2=relu.
// OUTF32: write fp32 C (for cproj / logits), else bf16.
// ---------------------------------------------------------------------------
template <int ACT, bool RES, bool OUTF32>
__launch_bounds__(256, 2)
__global__ void gemm_bf16_kernel(const short* __restrict__ A, const short* __restrict__ W,
                                 const float* __restrict__ bias, const short* __restrict__ res,
                                 void* __restrict__ Cv, int M, int N, int K) {
  __shared__ __align__(16) short As[128 * 64];
  __shared__ __align__(16) short Ws[128 * 64];
  const int t  = threadIdx.x;
  const int w  = t >> 6;          // wave 0..3
  const int l  = t & 63;
  const int wr = w >> 1;          // wave row (2)
  const int wc = w & 1;           // wave col (2)
  const int lr = l & 15;          // fragment row lane
  const int kg = l >> 4;          // k-group 0..3
  const int nbn = N / 128;
  const int bid = xcd_swz(blockIdx.x, gridDim.x);
  const int bm = bid / nbn;       // per-XCD contiguous bm -> A panel L2 reuse
  const int bn = bid % nbn;
  const int m0 = bm * 128, n0 = bn * 128;

  f32x4 acc[4][4] = {};

  // staging geometry: 16 chunks/operand (8 rows x 64 shorts = 1024 B each);
  // wave w stages chunks w*4..w*4+3. lane: row-in-chunk rg, swizzled col cs.
  const int rg = l >> 3;                      // 0..7
  const int cs = ((l & 7) ^ rg) * 8;          // pre-swizzled source col (shorts)
  const int swz = (lr & 7) * 8;               // read-side XOR (shorts)

  for (int k0 = 0; k0 < K; k0 += 64) {
    const short* Ab = &A[(size_t)m0 * K + k0 + cs];
    const short* Wb = &W[(size_t)n0 * K + k0 + cs];
#pragma unroll
    for (int q = 0; q < 4; ++q) {
      const int i = w * 4 + q;
      const int row = i * 8 + rg;
      gload_lds16(Ab + (size_t)row * K, &As[i * 512]);
      gload_lds16(Wb + (size_t)row * K, &Ws[i * 512]);
    }
    __syncthreads();  // compiler drains vmcnt(0) before s_barrier

#pragma unroll
    for (int kk = 0; kk < 64; kk += 32) {
      short8 af[4], bf[4];
#pragma unroll
      for (int mi = 0; mi < 4; ++mi)
        af[mi] = *(const short8*)&As[(wr * 64 + mi * 16 + lr) * 64 + ((kk + kg * 8) ^ swz)];
#pragma unroll
      for (int ni = 0; ni < 4; ++ni)
        bf[ni] = *(const short8*)&Ws[(wc * 64 + ni * 16 + lr) * 64 + ((kk + kg * 8) ^ swz)];
#pragma unroll
      for (int mi = 0; mi < 4; ++mi)
#pragma unroll
        for (int ni = 0; ni < 4; ++ni)
          acc[mi][ni] = __builtin_amdgcn_mfma_f32_16x16x32_bf16(af[mi], bf[ni], acc[mi][ni], 0, 0, 0);
    }
    __syncthreads();
  }

  float* Cf = (float*)Cv;
  short* Cb = (short*)Cv;
  // epilogue: C/D layout col=l&15, row=(l>>4)*4+j  [m89-verified]
#pragma unroll
  for (int ni = 0; ni < 4; ++ni) {
    const int n = n0 + wc * 64 + ni * 16 + lr;
    const float bv = bias[n];
#pragma unroll
    for (int mi = 0; mi < 4; ++mi) {
      const int mbase = m0 + wr * 64 + mi * 16 + kg * 4;
#pragma unroll
      for (int j = 0; j < 4; ++j) {
        float z = acc[mi][ni][j] + bv;
        const size_t off = (size_t)(mbase + j) * N + n;
        if (RES) z += b2f(res[off]);
        if (ACT == 1) z = 0.5f * z * (1.0f + erff(z * 0.70710678118654752f));
        if (ACT == 2) z = fmaxf(z, 0.0f);
        if (OUTF32) Cf[off] = z;
        else        Cb[off] = (short)bfround(z);
      }
    }
  }
}

// ---------------------------------------------------------------------------
// Fused GEMM + residual + LayerNorm, N=256 exactly:
//   out[M,256] = LN( A[M,K] @ W[256,K]^T + bias + res ) * g + b   (bf16 out)
// Tile 64x256, 256 threads = 4 waves (2 wr x 2 wc); per-wave 32x128 =
// 2x8 16x16 frags (64 acc VGPR). Same staging/swizzle algebra as
// gemm_bf16_kernel (frag-row & 7 == lr & 7 holds for all rows here too).
// z kept fp32 through the LN (more accurate than the old bf16 roundtrip).
// Row stats: in-reg over ni, shfl_xor over the 16 lr lanes, 1KB LDS
// cross-wave (wc) exchange. In-place out==res is safe: each lane reads res
// only for rows its block owns, all res reads precede the __syncthreads()
// that precedes all out writes, and blocks own disjoint rows.
// ---------------------------------------------------------------------------
__launch_bounds__(256, 2)
__global__ void gemm_ln_kernel(const short* __restrict__ A, const short* __restrict__ W,
                               const float* __restrict__ bias, const short* __restrict__ res,
                               const float* __restrict__ g, const float* __restrict__ bb,
                               short* __restrict__ out, int M, int K) {
  __shared__ __align__(16) short As[64 * 64];
  __shared__ __align__(16) short Ws[256 * 64];
  __shared__ float lnbuf[64][2][2];   // [row][wc][{s1,s2}]
  const int t  = threadIdx.x;
  const int w  = t >> 6;
  const int l  = t & 63;
  const int wr = w >> 1;
  const int wc = w & 1;
  const int lr = l & 15;
  const int kg = l >> 4;
  const int bid = xcd_swz(blockIdx.x, gridDim.x);
  const int m0 = bid * 64;

  f32x4 acc[2][8] = {};

  const int rg = l >> 3;
  const int cs = ((l & 7) ^ rg) * 8;
  const int swz = (lr & 7) * 8;

  for (int k0 = 0; k0 < K; k0 += 64) {
    const short* Ab = &A[(size_t)m0 * K + k0 + cs];
    const short* Wb = &W[(size_t)0 * K + k0 + cs];
#pragma unroll
    for (int q = 0; q < 2; ++q) {         // A: 8 chunks, 2 per wave
      const int i = w * 2 + q;
      gload_lds16(Ab + (size_t)(i * 8 + rg) * K, &As[i * 512]);
    }
#pragma unroll
    for (int q = 0; q < 8; ++q) {         // W: 32 chunks, 8 per wave
      const int i = w * 8 + q;
      gload_lds16(Wb + (size_t)(i * 8 + rg) * K, &Ws[i * 512]);
    }
    __syncthreads();

#pragma unroll
    for (int kk = 0; kk < 64; kk += 32) {
      short8 af[2], bf[8];
#pragma unroll
      for (int mi = 0; mi < 2; ++mi)
        af[mi] = *(const short8*)&As[(wr * 32 + mi * 16 + lr) * 64 + ((kk + kg * 8) ^ swz)];
#pragma unroll
      for (int ni = 0; ni < 8; ++ni)
        bf[ni] = *(const short8*)&Ws[(wc * 128 + ni * 16 + lr) * 64 + ((kk + kg * 8) ^ swz)];
#pragma unroll
      for (int mi = 0; mi < 2; ++mi)
#pragma unroll
        for (int ni = 0; ni < 8; ++ni)
          acc[mi][ni] = __builtin_amdgcn_mfma_f32_16x16x32_bf16(af[mi], bf[ni], acc[mi][ni], 0, 0, 0);
    }
    __syncthreads();
  }

  // z = acc + bias + res (fp32, stored back into acc); accumulate row partials
  float biasv[8], gv[8], bv[8];
#pragma unroll
  for (int ni = 0; ni < 8; ++ni) {
    const int n = wc * 128 + ni * 16 + lr;
    biasv[ni] = bias[n]; gv[ni] = g[n]; bv[ni] = bb[n];
  }
  float ps1[2][4] = {}, ps2[2][4] = {};
#pragma unroll
  for (int mi = 0; mi < 2; ++mi)
#pragma unroll
    for (int j = 0; j < 4; ++j) {
      const int m = m0 + wr * 32 + mi * 16 + kg * 4 + j;
#pragma unroll
      for (int ni = 0; ni < 8; ++ni) {
        const int n = wc * 128 + ni * 16 + lr;
        float z = acc[mi][ni][j] + biasv[ni] + b2f(res[(size_t)m * 256 + n]);
        acc[mi][ni][j] = z;
        ps1[mi][j] += z;
        ps2[mi][j] = fmaf(z, z, ps2[mi][j]);
      }
    }
  // reduce across the 16 lr lanes (off<16 keeps kg groups separate)
#pragma unroll
  for (int off = 1; off <= 8; off <<= 1) {
#pragma unroll
    for (int mi = 0; mi < 2; ++mi)
#pragma unroll
      for (int j = 0; j < 4; ++j) {
        ps1[mi][j] += __shfl_xor(ps1[mi][j], off);
        ps2[mi][j] += __shfl_xor(ps2[mi][j], off);
      }
  }
  if (lr == 0) {
#pragma unroll
    for (int mi = 0; mi < 2; ++mi)
#pragma unroll
      for (int j = 0; j < 4; ++j) {
        const int r = wr * 32 + mi * 16 + kg * 4 + j;
        lnbuf[r][wc][0] = ps1[mi][j];
        lnbuf[r][wc][1] = ps2[mi][j];
      }
  }
  __syncthreads();

#pragma unroll
  for (int mi = 0; mi < 2; ++mi)
#pragma unroll
    for (int j = 0; j < 4; ++j) {
      const int r = wr * 32 + mi * 16 + kg * 4 + j;
      const float s1 = lnbuf[r][0][0] + lnbuf[r][1][0];
      const float s2 = lnbuf[r][0][1] + lnbuf[r][1][1];
      const float mu  = s1 * (1.0f / 256.0f);
      const float var = s2 * (1.0f / 256.0f) - mu * mu;
      const float rs  = 1.0f / sqrtf(var + 1e-5f);
      const size_t mrow = (size_t)(m0 + r) * 256;
#pragma unroll
      for (int ni = 0; ni < 8; ++ni) {
        const int n = wc * 128 + ni * 16 + lr;
        out[mrow + n] = (short)bfround((acc[mi][ni][j] - mu) * rs * gv[ni] + bv[ni]);
      }
    }
}

// ---------------------------------------------------------------------------
// Embedding (chunk-local bf16 h): h[t,:] = (s==0?0:x_emb[x[b,s-1]]) + pos_emb[s]
//                                         + cproj[b],  b = b0 + t/16, s = t%16
// ---------------------------------------------------------------------------
__global__ void embed_kernel(const int* __restrict__ x, const float* __restrict__ x_emb,
                             const float* __restrict__ pos_emb, const float* __restrict__ cproj,
                             short* __restrict__ h, int b0) {
  const int idx = blockIdx.x * 256 + threadIdx.x;
  const int e4 = idx & 63;
  const int s  = (idx >> 6) & 15;
  const int b  = b0 + (idx >> 10);
  const float4 pe = ((const float4*)pos_emb)[s * 64 + e4];
  const float4 cp = ((const float4*)cproj)[b * 64 + e4];
  float4 v;
  v.x = pe.x + cp.x; v.y = pe.y + cp.y; v.z = pe.z + cp.z; v.w = pe.w + cp.w;
  if (s > 0) {
    const int tok = x[b * 16 + s - 1];
    const float4 xe = ((const float4*)x_emb)[tok * 64 + e4];
    v.x += xe.x; v.y += xe.y; v.z += xe.z; v.w += xe.w;
  }
  uint2 p;
  p.x = pack2(v.x, v.y);
  p.y = pack2(v.z, v.w);
  ((uint2*)h)[idx] = p;
}

// ---------------------------------------------------------------------------
// Attention (chunk-local, bf16 I/O): per (b_local, head) on one wave. S=16, dh=32.
// qkv [MC,768] bf16: 0..255 q, 256..511 k, 512..767 v; head hh at hh*32.
// ---------------------------------------------------------------------------
__launch_bounds__(256)
__global__ void attn_kernel(const short* __restrict__ qkv, short* __restrict__ o) {
  __shared__ __align__(16) float sq[4][16][36];
  __shared__ __align__(16) float sk[4][16][36];
  __shared__ __align__(16) float sv[4][16][36];
  __shared__ float sa[4][16][17];
  const int w   = threadIdx.x >> 6;
  const int l   = threadIdx.x & 63;
  const int gid = blockIdx.x * 4 + w;   // = b_local*8 + head
  const int b   = gid >> 3;
  const int hh  = gid & 7;

  {  // cooperative load+convert: 16 rows x 32 d, 4 lanes/row, 8 bf16 per seg
    const int s  = l >> 2;
    const int d0 = (l & 3) * 8;
    const size_t base = (size_t)(b * 16 + s) * 768 + hh * 32 + d0;
    const uint4 qv = *(const uint4*)&qkv[base];
    const uint4 kv = *(const uint4*)&qkv[base + 256];
    const uint4 vv = *(const uint4*)&qkv[base + 512];
    float* dq = &sq[w][s][d0];
    float* dk = &sk[w][s][d0];
    float* dv = &sv[w][s][d0];
    dq[0] = blo(qv.x); dq[1] = bhi(qv.x); dq[2] = blo(qv.y); dq[3] = bhi(qv.y);
    dq[4] = blo(qv.z); dq[5] = bhi(qv.z); dq[6] = blo(qv.w); dq[7] = bhi(qv.w);
    dk[0] = blo(kv.x); dk[1] = bhi(kv.x); dk[2] = blo(kv.y); dk[3] = bhi(kv.y);
    dk[4] = blo(kv.z); dk[5] = bhi(kv.z); dk[6] = blo(kv.w); dk[7] = bhi(kv.w);
    dv[0] = blo(vv.x); dv[1] = bhi(vv.x); dv[2] = blo(vv.y); dv[3] = bhi(vv.y);
    dv[4] = blo(vv.z); dv[5] = bhi(vv.z); dv[6] = blo(vv.w); dv[7] = bhi(vv.w);
  }
  __syncthreads();

  {  // scores + causal softmax: lane owns row sr, 4 cols t = tq*4+j
    const int sr = l & 15;
    const int tq = l >> 4;
    float sc[4] = {0.f, 0.f, 0.f, 0.f};
    for (int d = 0; d < 32; d += 4) {
      const float4 qv = *(const float4*)&sq[w][sr][d];
#pragma unroll
      for (int j = 0; j < 4; ++j) {
        const float4 kv = *(const float4*)&sk[w][tq * 4 + j][d];
        sc[j] += qv.x * kv.x + qv.y * kv.y + qv.z * kv.z + qv.w * kv.w;
      }
    }
    float mx = -1e30f;
#pragma unroll
    for (int j = 0; j < 4; ++j) {
      const int tt = tq * 4 + j;
      sc[j] = (tt > sr) ? -1e30f : sc[j] * 0.17677669529663687f;  // 1/sqrt(32)
      mx = fmaxf(mx, sc[j]);
    }
    mx = fmaxf(mx, __shfl_xor(mx, 16));
    mx = fmaxf(mx, __shfl_xor(mx, 32));
    float e[4]; float sm = 0.f;
#pragma unroll
    for (int j = 0; j < 4; ++j) { e[j] = expf(sc[j] - mx); sm += e[j]; }
    sm += __shfl_xor(sm, 16);
    sm += __shfl_xor(sm, 32);
#pragma unroll
    for (int j = 0; j < 4; ++j) sa[w][sr][tq * 4 + j] = e[j] / sm;
  }
  __syncthreads();

  {  // o[s,d] = sum_t a[s,t] * v[t,d]; pack 8 bf16 per lane (16B store)
    const int s  = l >> 2;
    const int d0 = (l & 3) * 8;
    float a0[4] = {0.f, 0.f, 0.f, 0.f}, a1[4] = {0.f, 0.f, 0.f, 0.f};
    for (int tt = 0; tt < 16; ++tt) {
      const float av = sa[w][s][tt];
      const float4 v0 = *(const float4*)&sv[w][tt][d0];
      const float4 v1 = *(const float4*)&sv[w][tt][d0 + 4];
      a0[0] = fmaf(av, v0.x, a0[0]); a0[1] = fmaf(av, v0.y, a0[1]);
      a0[2] = fmaf(av, v0.z, a0[2]); a0[3] = fmaf(av, v0.w, a0[3]);
      a1[0] = fmaf(av, v1.x, a1[0]); a1[1] = fmaf(av, v1.y, a1[1]);
      a1[2] = fmaf(av, v1.z, a1[2]); a1[3] = fmaf(av, v1.w, a1[3]);
    }
    const size_t ob = (size_t)(b * 16 + s) * 256 + hh * 32 + d0;
    uint4 p;
    p.x = pack2(a0[0], a0[1]); p.y = pack2(a0[2], a0[3]);
    p.z = pack2(a1[0], a1[1]); p.w = pack2(a1[2], a1[3]);
    *(uint4*)&o[ob] = p;
  }
}

// ---------------------------------------------------------------------------
// Final: out[b] = sum_s ( logits[s_local, x[b,s]] - logsumexp_v )
// logits chunk-local [MC, 512] fp32; one wave per b; 8 elements/lane.
// ---------------------------------------------------------------------------
__launch_bounds__(256)
__global__ void logprob_kernel(const float* __restrict__ logits, const int* __restrict__ x,
                               float* __restrict__ out, int b0) {
  const int w  = threadIdx.x >> 6;
  const int l  = threadIdx.x & 63;
  const int bl = blockIdx.x * 4 + w;
  const int b  = b0 + bl;
  float acc = 0.f;
  for (int s = 0; s < 16; ++s) {
    const float* row = logits + (size_t)(bl * 16 + s) * 512;
    float v[8];
#pragma unroll
    for (int i = 0; i < 8; ++i) v[i] = row[l + 64 * i];
    float mx = v[0];
#pragma unroll
    for (int i = 1; i < 8; ++i) mx = fmaxf(mx, v[i]);
    mx = wave_max(mx);
    float se = 0.f;
#pragma unroll
    for (int i = 0; i < 8; ++i) se += expf(v[i] - mx);
    se = wave_sum(se);
    const float lse = mx + logf(se);
    const float picked = row[x[b * 16 + s]];
    acc += picked - lse;
  }
  if (l == 0) out[b] = acc;
}

// ---------------------------------------------------------------------------
// Orchestration. Workspace: bf16 weights+c (14.2 MB) | cpr [B_,256] f32 (8 MB)
// | h [MC,256] bf16 | R [MC,1024] bf16 | X [MC,1024] bf16.
// logits (fp32 [MC,512]) aliases R's bytes exactly. Adaptive BC chunking.
// Per layer: qkv->R, attn->X, fused{Wo+res+LN1}->h (in-place res), FF1->R,
// fused{FF2+res+LN2}->h. Head unchanged.
// ---------------------------------------------------------------------------
extern "C" void kernel_launch(void* const* d_in, const int* in_sizes, int n_in,
                              void* d_out, int out_size, void* d_ws, size_t ws_size,
                              hipStream_t stream) {
  const int*   x       = (const int*)  d_in[0];
  const float* c       = (const float*)d_in[1];
  const float* x_emb   = (const float*)d_in[2];
  const float* pos_emb = (const float*)d_in[3];
  const float* c_W     = (const float*)d_in[4];
  const float* c_b     = (const float*)d_in[5];
  const float* Wqkv    = (const float*)d_in[6];
  const float* bqkv    = (const float*)d_in[7];
  const float* Wo      = (const float*)d_in[8];
  const float* bo      = (const float*)d_in[9];
  const float* ln1_g   = (const float*)d_in[10];
  const float* ln1_b   = (const float*)d_in[11];
  const float* W1      = (const float*)d_in[12];
  const float* b1      = (const float*)d_in[13];
  const float* W2      = (const float*)d_in[14];
  const float* b2      = (const float*)d_in[15];
  const float* ln2_g   = (const float*)d_in[16];
  const float* ln2_b   = (const float*)d_in[17];
  const float* mW0     = (const float*)d_in[18];
  const float* mb0     = (const float*)d_in[19];
  const float* mW1     = (const float*)d_in[20];
  const float* mb1     = (const float*)d_in[21];
  const float* mW2     = (const float*)d_in[22];
  const float* mb2     = (const float*)d_in[23];
  float* out = (float*)d_out;

  // bf16 region element counts
  const size_t nWqkv = (size_t)L_ * 768 * 256;
  const size_t nWo   = (size_t)L_ * 256 * 256;
  const size_t nW1   = (size_t)L_ * 1024 * 256;
  const size_t nW2   = (size_t)L_ * 256 * 1024;
  const size_t nmW0  = (size_t)U_ * E_;
  const size_t nmW1  = (size_t)U_ * U_;
  const size_t nmW2  = (size_t)V_ * U_;
  const size_t ncW   = (size_t)E_ * DC_;
  const size_t nC    = (size_t)B_ * DC_;
  const size_t WBF   = nWqkv + nWo + nW1 + nW2 + nmW0 + nmW1 + nmW2 + ncW + nC;

  short* bWqkv = (short*)d_ws;
  short* bWo   = bWqkv + nWqkv;
  short* bW1   = bWo   + nWo;
  short* bW2   = bW1   + nW1;
  short* bmW0  = bW2   + nW2;
  short* bmW1  = bmW0  + nmW0;
  short* bmW2  = bmW1  + nmW1;
  short* bcW   = bmW2  + nmW2;
  short* bC    = bcW   + ncW;

  // Pick largest chunk (rows) that fits after weights + cpr.
  const size_t fixed_bytes = WBF * 2 + (size_t)B_ * 256 * 4;
  int BC = 0;
  for (int bc = B_; bc >= 128; bc >>= 1) {
    const size_t need = fixed_bytes + (size_t)bc * 16 * 2304 * 2;  // bf16 activations
    if (need <= ws_size) { BC = bc; break; }
  }
  if (BC == 0) return;  // fail visibly via graph node count
  const int MC = BC * 16;
  const int NCHUNK = B_ / BC;

  float* cpr = (float*)((char*)d_ws + WBF * 2);
  short* h   = (short*)(cpr + (size_t)B_ * 256);
  short* R   = h + (size_t)MC * 256;
  short* X   = R + (size_t)MC * 1024;
  float* logitsF = (float*)R;  // [MC,512] fp32 aliases R's bytes exactly

  const dim3 blk(256);

  // Convert weights (+ c input) fp32 -> bf16 each call (d_ws is re-poisoned).
  w2bf_kernel<<<dim3(nWqkv / 1024), blk, 0, stream>>>(Wqkv, bWqkv);
  w2bf_kernel<<<dim3(nWo   / 1024), blk, 0, stream>>>(Wo,   bWo);
  w2bf_kernel<<<dim3(nW1   / 1024), blk, 0, stream>>>(W1,   bW1);
  w2bf_kernel<<<dim3(nW2   / 1024), blk, 0, stream>>>(W2,   bW2);
  w2bf_kernel<<<dim3(nmW0  / 1024), blk, 0, stream>>>(mW0,  bmW0);
  w2bf_kernel<<<dim3(nmW1  / 1024), blk, 0, stream>>>(mW1,  bmW1);
  w2bf_kernel<<<dim3(nmW2  / 1024), blk, 0, stream>>>(mW2,  bmW2);
  w2bf_kernel<<<dim3(ncW   / 1024), blk, 0, stream>>>(c_W,  bcW);
  w2bf_kernel<<<dim3(nC    / 1024), blk, 0, stream>>>(c,    bC);

  // cproj = c @ c_W^T + c_b   [B_,256] fp32, K=64  (whole batch, once)
  gemm_bf16_kernel<0, false, true><<<dim3((B_ / 128) * (E_ / 128)), blk, 0, stream>>>(
      bC, bcW, c_b, nullptr, cpr, B_, E_, DC_);

  for (int ci = 0; ci < NCHUNK; ++ci) {
    const int b0 = ci * BC;
    embed_kernel<<<dim3((MC * 64) / 256), blk, 0, stream>>>(x, x_emb, pos_emb, cpr, h, b0);

    for (int l = 0; l < L_; ++l) {
      // qkv = h @ Wqkv^T + bqkv   [MC,768] bf16, K=256  -> R
      gemm_bf16_kernel<0, false, false><<<dim3((MC / 128) * (768 / 128)), blk, 0, stream>>>(
          h, bWqkv + (size_t)l * 768 * 256, bqkv + (size_t)l * 768, nullptr, R, MC, 768, 256);
      // o = attention(qkv)   [MC,256] bf16  -> X
      attn_kernel<<<dim3(BC * 2), blk, 0, stream>>>(R, X);
      // h = LN1( X @ Wo^T + bo + h )   fused, in-place on h, K=256
      gemm_ln_kernel<<<dim3(MC / 64), blk, 0, stream>>>(
          X, bWo + (size_t)l * 256 * 256, bo + (size_t)l * 256, h,
          ln1_g + (size_t)l * 256, ln1_b + (size_t)l * 256, h, MC, 256);
      // f = gelu(h @ W1^T + b1)   [MC,1024] bf16, K=256  -> R
      gemm_bf16_kernel<1, false, false><<<dim3((MC / 128) * (FF_ / 128)), blk, 0, stream>>>(
          h, bW1 + (size_t)l * 1024 * 256, b1 + (size_t)l * 1024, nullptr, R, MC, 1024, 256);
      // h = LN2( R @ W2^T + b2 + h )   fused, in-place on h, K=1024
      gemm_ln_kernel<<<dim3(MC / 64), blk, 0, stream>>>(
          R, bW2 + (size_t)l * 256 * 1024, b2 + (size_t)l * 256, h,
          ln2_g + (size_t)l * 256, ln2_b + (size_t)l * 256, h, MC, 1024);
    }

    // Head MLP (chunk-local)
    gemm_bf16_kernel<2, false, false><<<dim3((MC / 128) * (U_ / 128)), blk, 0, stream>>>(
        h, bmW0, mb0, nullptr, R, MC, U_, E_);           // z0 = relu(.) -> R (bf16)
    gemm_bf16_kernel<2, false, false><<<dim3((MC / 128) * (U_ / 128)), blk, 0, stream>>>(
        R, bmW1, mb1, nullptr, X, MC, U_, U_);           // z1 = relu(.) -> X (bf16)
    gemm_bf16_kernel<0, false, true><<<dim3((MC / 128) * (V_ / 128)), blk, 0, stream>>>(
        X, bmW2, mb2, nullptr, logitsF, MC, V_, U_);     // logits -> R bytes (fp32)

    logprob_kernel<<<dim3(BC / 4), blk, 0, stream>>>(logitsF, x, out, b0);
  }
}